// Round 8
// baseline (760.474 us; speedup 1.0000x reference)
//
#include <hip/hip_runtime.h>
#include <math.h>

#define DM   2048
#define DFF  8192
#define NH   16
#define HD   128
#define SEQ  2048
#define MROWS 4096   // BATCH * SEQ

typedef __attribute__((ext_vector_type(4))) float  f32x4;
typedef __attribute__((ext_vector_type(8))) __bf16 bf16x8;
typedef __attribute__((ext_vector_type(4))) short  short4_t;

#define VMCNT(n) asm volatile("s_waitcnt vmcnt(" #n ")" ::: "memory")
#define LGKM0()  asm volatile("s_waitcnt lgkmcnt(0)" ::: "memory")
#define SBAR()   asm volatile("s_barrier" ::: "memory")
#define SCHEDB() __builtin_amdgcn_sched_barrier(0)

__device__ inline unsigned short f2bf(float f) {
  union { float f; unsigned int u; } x; x.f = f;
  unsigned int r = x.u + 0x7FFFu + ((x.u >> 16) & 1u);
  return (unsigned short)(r >> 16);
}

__device__ inline void gload16(const void* g, void* l) {
  __builtin_amdgcn_global_load_lds(
      (const __attribute__((address_space(1))) unsigned int*)g,
      (__attribute__((address_space(3))) unsigned int*)l, 16, 0, 0);
}

// ---------------- LayerNorm (f32 in, bf16 out) ----------------
__global__ __launch_bounds__(256) void ln_kernel(
    const float* __restrict__ in, const float* __restrict__ gw,
    const float* __restrict__ bw, unsigned short* __restrict__ out)
{
  const int row = blockIdx.x;
  const float* xr = in + (size_t)row * DM;
  const int t = threadIdx.x, lane = t & 63, w = t >> 6;
  float4 v0 = ((const float4*)xr)[t];
  float4 v1 = ((const float4*)xr)[t + 256];
  float s = v0.x+v0.y+v0.z+v0.w + v1.x+v1.y+v1.z+v1.w;
  float s2 = v0.x*v0.x+v0.y*v0.y+v0.z*v0.z+v0.w*v0.w
           + v1.x*v1.x+v1.y*v1.y+v1.z*v1.z+v1.w*v1.w;
  #pragma unroll
  for (int off = 32; off; off >>= 1) { s += __shfl_xor(s, off); s2 += __shfl_xor(s2, off); }
  __shared__ float rs[4], rs2[4];
  if (lane == 0) { rs[w] = s; rs2[w] = s2; }
  __syncthreads();
  s = rs[0] + rs[1] + rs[2] + rs[3];
  s2 = rs2[0] + rs2[1] + rs2[2] + rs2[3];
  const float mu = s * (1.0f / DM);
  const float var = s2 * (1.0f / DM) - mu * mu;
  const float rstd = rsqrtf(var + 1e-5f);
  float4 g0 = ((const float4*)gw)[t],     b0 = ((const float4*)bw)[t];
  float4 g1 = ((const float4*)gw)[t+256], b1 = ((const float4*)bw)[t+256];
  unsigned short* o = out + (size_t)row * DM;
  int i0 = t * 4, i1 = (t + 256) * 4;
  o[i0+0] = f2bf((v0.x-mu)*rstd*g0.x + b0.x);
  o[i0+1] = f2bf((v0.y-mu)*rstd*g0.y + b0.y);
  o[i0+2] = f2bf((v0.z-mu)*rstd*g0.z + b0.z);
  o[i0+3] = f2bf((v0.w-mu)*rstd*g0.w + b0.w);
  o[i1+0] = f2bf((v1.x-mu)*rstd*g1.x + b1.x);
  o[i1+1] = f2bf((v1.y-mu)*rstd*g1.y + b1.y);
  o[i1+2] = f2bf((v1.z-mu)*rstd*g1.z + b1.z);
  o[i1+3] = f2bf((v1.w-mu)*rstd*g1.w + b1.w);
}

// ---- LN2 variant: also pre-fills pre[row] = h[row] + b2 (f32) for FFN2 atomics ----
__global__ __launch_bounds__(256) void ln2_kernel(
    const float* __restrict__ in, const float* __restrict__ gw,
    const float* __restrict__ bw, unsigned short* __restrict__ out,
    float* __restrict__ pre, const float* __restrict__ bias2)
{
  const int row = blockIdx.x;
  const float* xr = in + (size_t)row * DM;
  const int t = threadIdx.x, lane = t & 63, w = t >> 6;
  float4 v0 = ((const float4*)xr)[t];
  float4 v1 = ((const float4*)xr)[t + 256];
  float s = v0.x+v0.y+v0.z+v0.w + v1.x+v1.y+v1.z+v1.w;
  float s2 = v0.x*v0.x+v0.y*v0.y+v0.z*v0.z+v0.w*v0.w
           + v1.x*v1.x+v1.y*v1.y+v1.z*v1.z+v1.w*v1.w;
  #pragma unroll
  for (int off = 32; off; off >>= 1) { s += __shfl_xor(s, off); s2 += __shfl_xor(s2, off); }
  __shared__ float rs[4], rs2[4];
  if (lane == 0) { rs[w] = s; rs2[w] = s2; }
  __syncthreads();
  s = rs[0] + rs[1] + rs[2] + rs[3];
  s2 = rs2[0] + rs2[1] + rs2[2] + rs2[3];
  const float mu = s * (1.0f / DM);
  const float var = s2 * (1.0f / DM) - mu * mu;
  const float rstd = rsqrtf(var + 1e-5f);
  float4 g0 = ((const float4*)gw)[t],     b0 = ((const float4*)bw)[t];
  float4 g1 = ((const float4*)gw)[t+256], b1 = ((const float4*)bw)[t+256];
  float4 q0 = ((const float4*)bias2)[t], q1 = ((const float4*)bias2)[t+256];
  unsigned short* o = out + (size_t)row * DM;
  float* pr = pre + (size_t)row * DM;
  int i0 = t * 4, i1 = (t + 256) * 4;
  o[i0+0] = f2bf((v0.x-mu)*rstd*g0.x + b0.x);
  o[i0+1] = f2bf((v0.y-mu)*rstd*g0.y + b0.y);
  o[i0+2] = f2bf((v0.z-mu)*rstd*g0.z + b0.z);
  o[i0+3] = f2bf((v0.w-mu)*rstd*g0.w + b0.w);
  o[i1+0] = f2bf((v1.x-mu)*rstd*g1.x + b1.x);
  o[i1+1] = f2bf((v1.y-mu)*rstd*g1.y + b1.y);
  o[i1+2] = f2bf((v1.z-mu)*rstd*g1.z + b1.z);
  o[i1+3] = f2bf((v1.w-mu)*rstd*g1.w + b1.w);
  float4 p0, p1;
  p0.x = v0.x + q0.x; p0.y = v0.y + q0.y; p0.z = v0.z + q0.z; p0.w = v0.w + q0.w;
  p1.x = v1.x + q1.x; p1.y = v1.y + q1.y; p1.z = v1.z + q1.z; p1.w = v1.w + q1.w;
  ((float4*)pr)[t] = p0;
  ((float4*)pr)[t + 256] = p1;
}

// ------- weight transpose + f32->bf16: in[nrows][ncols] -> out[ncols][nrows] -------
__global__ void transpose_kernel(const float* __restrict__ in,
                                 unsigned short* __restrict__ out,
                                 int nrows, int ncols)
{
  __shared__ float tile[32][33];
  const int bx = blockIdx.x * 32;
  const int by = blockIdx.y * 32;
  const int tx = threadIdx.x, ty = threadIdx.y;
  #pragma unroll
  for (int i = ty; i < 32; i += 8)
    tile[i][tx] = in[(size_t)(by + i) * ncols + bx + tx];
  __syncthreads();
  #pragma unroll
  for (int i = ty; i < 32; i += 8)
    out[(size_t)(bx + i) * nrows + by + tx] = f2bf(tile[tx][i]);
}

// ------- batched transpose of the 4 DM x DM weights into wt -------
__global__ void transpose4_kernel(const float* __restrict__ w0,
                                  const float* __restrict__ w1,
                                  const float* __restrict__ w2,
                                  const float* __restrict__ w3,
                                  unsigned short* __restrict__ out)
{
  __shared__ float tile[32][33];
  const float* srcs[4] = {w0, w1, w2, w3};
  const float* in = srcs[blockIdx.z];
  unsigned short* o = out + (size_t)blockIdx.z * DM * DM;
  const int bx = blockIdx.x * 32;
  const int by = blockIdx.y * 32;
  const int tx = threadIdx.x, ty = threadIdx.y;
  #pragma unroll
  for (int i = ty; i < 32; i += 8)
    tile[i][tx] = in[(size_t)(by + i) * DM + bx + tx];
  __syncthreads();
  #pragma unroll
  for (int i = ty; i < 32; i += 8)
    o[(size_t)(bx + i) * DM + by + tx] = f2bf(tile[tx][i]);
}

// ---- GEMM 256x256, BK=64, 8 waves (2Mx4N), per-wave 128x64 (m201 geometry). ----
// C = A[M][Kfull](bf16) @ Bt[N][Kfull]^T, K = per-block extent (split-K via gridDim.z).
// LDS: 2 slots x {A[256][64] | B[256][64]} = 128KB, chunk-swizzled (chunk ^= row&7,
// both sides -> involution; measured 0 conflicts in r6/r7).
// 4 phases/K-tile x 16 MFMA, quadrants (mh,nh); region staging with derived freedom:
//   ph0 reads A-mh0+B-nh0, stages B1(T+1) (region freed at ph1(T-1));
//   ph1 reads B-nh1,       stages A0(T+2) (freed ph0);
//   ph2 reads A-mh1,       stages B0(T+2) (freed ph0);
//   ph3 no reads,          stages A1(T+2) (freed ph2); boundary vmcnt(6) (3 regions
//   x 2 loads stay in flight -- never drained in steady state).
enum { EP_QKV = 0, EP_FFN1 = 1, EP_ATOMIC = 2 };

template <int MODE>
__global__ __launch_bounds__(512, 2) void gemm_kernel(
    const unsigned short* __restrict__ A,
    const unsigned short* __restrict__ Bt,
    int K, int kstride, int N,
    const float* __restrict__ bias,
    void* __restrict__ out)
{
  __shared__ unsigned short lds[2][32768];   // [slot][ A 16384 | B 16384 ] shorts

  const int t = threadIdx.x;
  const int w = t >> 6, lane = t & 63;
  const int wm = w >> 2, wn = w & 3;
  const int c = lane & 15, g = lane >> 4;

  const long bm = (long)blockIdx.x * 256;
  const long bn = (long)blockIdx.y * 256;
  const long koff = (long)blockIdx.z * K;
  const int NT = K >> 6;
  const size_t ks = (size_t)kstride;

  // staging thread map: 512 thr x 16B = 8KB/issue; region = 128 rows = 2 issues
  const int tr  = t >> 3;                    // 0..63
  const int tc8 = (t & 7) * 8;               // dest chunk (shorts)
  const int sch = ((t & 7) ^ (tr & 7)) * 8;  // inverse-swizzled source chunk

  auto stageA = [&](int T, int mh) {
    const int s = T & 1;
    const int r0 = mh * 64 + tr;             // rows r0 and r0+128
    gload16(A + (bm + r0) * ks + koff + T * 64 + sch,       &lds[s][r0 * 64 + tc8]);
    gload16(A + (bm + r0 + 128) * ks + koff + T * 64 + sch, &lds[s][(r0 + 128) * 64 + tc8]);
  };
  auto stageB = [&](int T, int nh) {
    const int s = T & 1;
    const int r0 = nh * 32 + (tr & 31) + (tr >> 5) * 64;
    gload16(Bt + (bn + r0) * ks + koff + T * 64 + sch,       &lds[s][16384 + r0 * 64 + tc8]);
    gload16(Bt + (bn + r0 + 128) * ks + koff + T * 64 + sch, &lds[s][16384 + (r0 + 128) * 64 + tc8]);
  };

  f32x4 acc[8][4];
  #pragma unroll
  for (int i = 0; i < 8; i++)
    #pragma unroll
    for (int j = 0; j < 4; j++) acc[i][j] = (f32x4){0.f, 0.f, 0.f, 0.f};

  // read-side offsets
  const int xo0 = ((0 + g) ^ (c & 7)) * 8;   // kk=0 chunk
  const int xo1 = ((4 + g) ^ (c & 7)) * 8;   // kk=1 chunk
  const int abase = (wm * 128 + c) * 64;
  const int bbase = 16384 + (wn * 64 + c) * 64;

  // prologue: tile0 all 4 regions + tile1 A0,B0,A1 (B1(1) staged at T=0 ph0)
  stageA(0, 0); stageB(0, 0); stageA(0, 1); stageB(0, 1);
  stageA(1, 0); stageB(1, 0); stageA(1, 1);
  VMCNT(6);
  SBAR();

  bf16x8 a[4][2], b0[2][2], b1[2][2];

  for (int T = 0; T < NT; T++) {
    const unsigned short* Ls = lds[T & 1];

    // ---- phase 0: read A-mh0 (8) + B-nh0 (4); stage B1(T+1); MFMA (mh0,nh0)
    #pragma unroll
    for (int mf = 0; mf < 4; mf++) {
      a[mf][0] = *(const bf16x8*)&Ls[abase + mf * 1024 + xo0];
      a[mf][1] = *(const bf16x8*)&Ls[abase + mf * 1024 + xo1];
    }
    #pragma unroll
    for (int nf = 0; nf < 2; nf++) {
      b0[nf][0] = *(const bf16x8*)&Ls[bbase + nf * 1024 + xo0];
      b0[nf][1] = *(const bf16x8*)&Ls[bbase + nf * 1024 + xo1];
    }
    if (T + 1 < NT) stageB(T + 1, 1);
    SBAR();
    LGKM0(); SCHEDB();
    __builtin_amdgcn_s_setprio(1);
    #pragma unroll
    for (int kk = 0; kk < 2; kk++)
      #pragma unroll
      for (int mf = 0; mf < 4; mf++)
        #pragma unroll
        for (int nf = 0; nf < 2; nf++)
          acc[mf][nf] = __builtin_amdgcn_mfma_f32_16x16x32_bf16(a[mf][kk], b0[nf][kk], acc[mf][nf], 0, 0, 0);
    __builtin_amdgcn_s_setprio(0);
    SBAR();

    // ---- phase 1: read B-nh1 (4); stage A0(T+2); MFMA (mh0,nh1)
    #pragma unroll
    for (int nf = 0; nf < 2; nf++) {
      b1[nf][0] = *(const bf16x8*)&Ls[bbase + 2048 + nf * 1024 + xo0];
      b1[nf][1] = *(const bf16x8*)&Ls[bbase + 2048 + nf * 1024 + xo1];
    }
    if (T + 2 < NT) stageA(T + 2, 0);
    SBAR();
    LGKM0(); SCHEDB();
    __builtin_amdgcn_s_setprio(1);
    #pragma unroll
    for (int kk = 0; kk < 2; kk++)
      #pragma unroll
      for (int mf = 0; mf < 4; mf++)
        #pragma unroll
        for (int nf = 0; nf < 2; nf++)
          acc[mf][2 + nf] = __builtin_amdgcn_mfma_f32_16x16x32_bf16(a[mf][kk], b1[nf][kk], acc[mf][2 + nf], 0, 0, 0);
    __builtin_amdgcn_s_setprio(0);
    SBAR();

    // ---- phase 2: read A-mh1 (8); stage B0(T+2); MFMA (mh1,nh0)
    #pragma unroll
    for (int mf = 0; mf < 4; mf++) {
      a[mf][0] = *(const bf16x8*)&Ls[abase + 4096 + mf * 1024 + xo0];
      a[mf][1] = *(const bf16x8*)&Ls[abase + 4096 + mf * 1024 + xo1];
    }
    if (T + 2 < NT) stageB(T + 2, 0);
    SBAR();
    LGKM0(); SCHEDB();
    __builtin_amdgcn_s_setprio(1);
    #pragma unroll
    for (int kk = 0; kk < 2; kk++)
      #pragma unroll
      for (int mf = 0; mf < 4; mf++)
        #pragma unroll
        for (int nf = 0; nf < 2; nf++)
          acc[4 + mf][nf] = __builtin_amdgcn_mfma_f32_16x16x32_bf16(a[mf][kk], b0[nf][kk], acc[4 + mf][nf], 0, 0, 0);
    __builtin_amdgcn_s_setprio(0);
    SBAR();

    // ---- phase 3: stage A1(T+2); MFMA (mh1,nh1); boundary counted vmcnt
    if (T + 2 < NT) stageA(T + 2, 1);
    __builtin_amdgcn_s_setprio(1);
    #pragma unroll
    for (int kk = 0; kk < 2; kk++)
      #pragma unroll
      for (int mf = 0; mf < 4; mf++)
        #pragma unroll
        for (int nf = 0; nf < 2; nf++)
          acc[4 + mf][2 + nf] = __builtin_amdgcn_mfma_f32_16x16x32_bf16(a[mf][kk], b1[nf][kk], acc[4 + mf][2 + nf], 0, 0, 0);
    __builtin_amdgcn_s_setprio(0);
    if (T + 2 < NT) { VMCNT(6); } else { VMCNT(0); }
    SBAR();
  }

  // ---------------- epilogue ----------------
  #pragma unroll
  for (int mf = 0; mf < 8; mf++) {
    const long row0 = bm + wm * 128 + mf * 16 + g * 4;
    #pragma unroll
    for (int nf = 0; nf < 4; nf++) {
      const long col = bn + wn * 64 + nf * 16 + c;
      #pragma unroll
      for (int r = 0; r < 4; r++) {
        const long row = row0 + r;
        float v = acc[mf][nf][r];
        if constexpr (MODE == EP_QKV) {
          const int slot = (int)(col >> 11);
          const long cc = col & 2047;
          const long hh = cc >> 7, dd = cc & 127;
          const long bb = row >> 11, ss = row & 2047;
          unsigned short* o = (unsigned short*)out;
          if (slot == 0)
            o[((bb * NH + hh) * SEQ + ss) * HD + dd] = f2bf(v * 0.08838834764831845f);
          else if (slot == 1)
            o[8388608 + ((bb * NH + hh) * SEQ + ss) * HD + dd] = f2bf(v);
          else
            o[16777216 + ((bb * NH + hh) * HD + dd) * SEQ + ss] = f2bf(v);
        } else if constexpr (MODE == EP_FFN1) {
          float u = v + bias[col];
          float y = 0.7978845608028654f * (u + 0.044715f * u * u * u);
          float e = __expf(-2.0f * fabsf(y));
          float th = (1.0f - e) / (1.0f + e);
          th = (y < 0.0f) ? -th : th;
          ((unsigned short*)out)[row * (long)N + col] = f2bf(0.5f * u * (1.0f + th));
        } else { // EP_ATOMIC: split-K partial accumulate into prefilled f32 buffer
          atomicAdd(&((float*)out)[row * (long)N + col], v);
        }
      }
    }
  }
}

// ---------------- Flash attention, causal + alibi, LDS-staged K/V ----------------
__global__ __launch_bounds__(256) void attn_kernel(
    const unsigned short* __restrict__ Q,
    const unsigned short* __restrict__ Kg,
    const unsigned short* __restrict__ Vt,
    const float* __restrict__ alibi,
    unsigned short* __restrict__ Out)
{
  __shared__ unsigned short lds[2][16384];   // 2 x (16KB K | 16KB V)

  const int bh = blockIdx.x;
  const int h = bh & (NH - 1);
  const int b = bh >> 4;
  const int j = blockIdx.y;                  // pair 0..15
  const int t = threadIdx.x;
  const int w = t >> 6;                      // wave 0..3
  const int lane = t & 63;
  const int c = lane & 15, g = lane >> 4;
  const int cx = (c & 7) << 4;               // read-side XOR swizzle

  const char* KpB = (const char*)(Kg + (size_t)bh * SEQ * HD);
  const char* VpB = (const char*)(Vt + (size_t)bh * SEQ * HD);
  const unsigned short* Qp = Q + (size_t)bh * SEQ * HD;
  const float* Ah = alibi + (size_t)h * SEQ * SEQ;

  #pragma unroll 1
  for (int half = 0; half < 2; half++) {
    const int cidx = half ? (31 - j) : j;
    const int nt = cidx + 1;
    const int qb = cidx * 64;
    const int q0 = qb + w * 16, qc = q0 + c;

    bf16x8 qf[4];
    #pragma unroll
    for (int dt = 0; dt < 4; dt++)
      qf[dt] = *(const bf16x8*)(Qp + (size_t)qc * HD + dt * 32 + g * 8);

    f32x4 oacc[8];
    #pragma unroll
    for (int d = 0; d < 8; d++) oacc[d] = (f32x4){0.f, 0.f, 0.f, 0.f};
    float m_run = -1e30f, s_run = 0.f;
    const float* Ap = Ah + (size_t)qc * SEQ;

    auto stage = [&](int tt, unsigned short* dst) {
      const size_t kvo = (size_t)tt * 64;
      #pragma unroll
      for (int k = 0; k < 8; k++) {
        const int o = w * 8192 + k * 1024 + lane * 16;
        if (w < 2) {
          const int so = o ^ (((o >> 8) & 7) << 4);
          gload16(KpB + kvo * 256 + so, dst + ((w * 8192 + k * 1024) >> 1));
        } else {
          const int o2 = o - 16384;
          const int d = o2 >> 7, win = o2 & 127;
          gload16(VpB + (size_t)d * 4096 + kvo * 2 + (win ^ ((d & 7) << 4)),
                  dst + ((w * 8192 + k * 1024) >> 1));
        }
      }
    };

    stage(0, lds[0]);
    __syncthreads();
    int buf = 0;

    for (int tt = 0; tt < nt; tt++) {
      if (tt + 1 < nt) stage(tt + 1, lds[buf ^ 1]);
      const unsigned short* LK = lds[buf];
      const unsigned short* LV = lds[buf] + 8192;
      const int kv0 = tt * 64;

      f32x4 sc[4];
      #pragma unroll
      for (int st = 0; st < 4; st++) sc[st] = (f32x4){0.f, 0.f, 0.f, 0.f};
      #pragma unroll
      for (int dt = 0; dt < 4; dt++)
        #pragma unroll
        for (int st = 0; st < 4; st++) {
          bf16x8 kf = *(const bf16x8*)&LK[(st * 4096 + c * 256 + ((dt * 64 + g * 16) ^ cx)) >> 1];
          sc[st] = __builtin_amdgcn_mfma_f32_16x16x32_bf16(kf, qf[dt], sc[st], 0, 0, 0);
        }

      float4 al[4];
      #pragma unroll
      for (int st = 0; st < 4; st++) al[st] = *(const float4*)(Ap + kv0 + st * 16 + g * 4);
      float scr[16];
      #pragma unroll
      for (int st = 0; st < 4; st++) {
        scr[st*4+0] = (kv0 + st*16 + g*4 + 0 > qc) ? -1e30f : sc[st][0] + al[st].x;
        scr[st*4+1] = (kv0 + st*16 + g*4 + 1 > qc) ? -1e30f : sc[st][1] + al[st].y;
        scr[st*4+2] = (kv0 + st*16 + g*4 + 2 > qc) ? -1e30f : sc[st][2] + al[st].z;
        scr[st*4+3] = (kv0 + st*16 + g*4 + 3 > qc) ? -1e30f : sc[st][3] + al[st].w;
      }

      float tm = scr[0];
      #pragma unroll
      for (int i = 1; i < 16; i++) tm = fmaxf(tm, scr[i]);
      tm = fmaxf(tm, __shfl_xor(tm, 16));
      tm = fmaxf(tm, __shfl_xor(tm, 32));
      const float m_new = fmaxf(m_run, tm);
      const float corr = __expf(m_run - m_new);
      float pv[16]; float ps = 0.f;
      #pragma unroll
      for (int i = 0; i < 16; i++) { pv[i] = __expf(scr[i] - m_new); ps += pv[i]; }
      ps += __shfl_xor(ps, 16);
      ps += __shfl_xor(ps, 32);
      s_run = s_run * corr + ps;
      m_run = m_new;

      short4_t pf[4];
      #pragma unroll
      for (int st = 0; st < 4; st++) {
        pf[st][0] = (short)f2bf(pv[st*4+0]); pf[st][1] = (short)f2bf(pv[st*4+1]);
        pf[st][2] = (short)f2bf(pv[st*4+2]); pf[st][3] = (short)f2bf(pv[st*4+3]);
      }

      float cf[4];
      #pragma unroll
      for (int r = 0; r < 4; r++) cf[r] = __shfl(corr, g * 4 + r);

      #pragma unroll
      for (int dt = 0; dt < 8; dt++) {
        f32x4 o = oacc[dt];
        o[0] *= cf[0]; o[1] *= cf[1]; o[2] *= cf[2]; o[3] *= cf[3];
        #pragma unroll
        for (int st = 0; st < 4; st++) {
          short4_t vf = *(const short4_t*)&LV[((dt * 16 + c) * 128 + ((st * 32 + g * 8) ^ cx)) >> 1];
          o = __builtin_amdgcn_mfma_f32_16x16x16bf16_1k(pf[st], vf, o, 0, 0, 0);
        }
        oacc[dt] = o;
      }

      __syncthreads();
      buf ^= 1;
    }

    float inv[4];
    #pragma unroll
    for (int r = 0; r < 4; r++) inv[r] = 1.0f / __shfl(s_run, g * 4 + r);
    #pragma unroll
    for (int dt = 0; dt < 8; dt++)
      #pragma unroll
      for (int r = 0; r < 4; r++)
        Out[(size_t)(b * SEQ + q0 + g * 4 + r) * DM + h * HD + dt * 16 + c] =
            f2bf(oacc[dt][r] * inv[r]);
  }
}

// ---------------- launch ----------------
extern "C" void kernel_launch(void* const* d_in, const int* in_sizes, int n_in,
                              void* d_out, int out_size, void* d_ws, size_t ws_size,
                              hipStream_t stream) {
  const float* x     = (const float*)d_in[0];
  const float* alibi = (const float*)d_in[1];
  const float* Wq    = (const float*)d_in[2];
  const float* Wk    = (const float*)d_in[3];
  const float* Wv    = (const float*)d_in[4];
  const float* Wo    = (const float*)d_in[5];
  const float* ln1g  = (const float*)d_in[6];
  const float* ln1b  = (const float*)d_in[7];
  const float* ln2g  = (const float*)d_in[8];
  const float* ln2b  = (const float*)d_in[9];
  const float* w1    = (const float*)d_in[10];
  const float* b1    = (const float*)d_in[11];
  const float* w2    = (const float*)d_in[12];
  const float* b2    = (const float*)d_in[13];

  char* ws = (char*)d_ws;
  float*          hbuf = (float*)(ws);                                // 32MB f32 h
  unsigned short* xn   = (unsigned short*)(ws + (32ull  << 20));      // 16MB bf16
  unsigned short* qb   = (unsigned short*)(ws + (48ull  << 20));      // Q|K|V 48MB
  unsigned short* kb   = (unsigned short*)(ws + (64ull  << 20));
  unsigned short* vt   = (unsigned short*)(ws + (80ull  << 20));
  unsigned short* ao   = (unsigned short*)(ws + (96ull  << 20));      // 16MB attn out
  unsigned short* wt   = (unsigned short*)(ws + (112ull << 20));      // 34MB weights
  unsigned short* a1   = (unsigned short*)(ws + (48ull  << 20));      // 64MB FFN1 out

  dim3 blk256(256);
  dim3 blk512(512);
  dim3 tb(32, 8);

  ln_kernel<<<MROWS, blk256, 0, stream>>>(x, ln1g, ln1b, xn);
  transpose4_kernel<<<dim3(DM/32, DM/32, 4), tb, 0, stream>>>(Wq, Wk, Wv, Wo, wt);

  // fused QKV: N=6144, epilogue routes by col>>11
  gemm_kernel<EP_QKV><<<dim3(MROWS/256, (3*DM)/256, 1), blk512, 0, stream>>>(
      xn, wt, DM, DM, 3*DM, nullptr, qb);

  attn_kernel<<<dim3(NH * 2, 16), blk256, 0, stream>>>(qb, kb, vt, alibi, ao);

  // WO: hbuf = x (prefill) + split-K=2 atomic accumulate of ao @ Wo^T
  hipMemcpyAsync(hbuf, x, (size_t)MROWS * DM * 4, hipMemcpyDeviceToDevice, stream);
  gemm_kernel<EP_ATOMIC><<<dim3(MROWS/256, DM/256, 2), blk512, 0, stream>>>(
      ao, wt + 3ull * DM * DM, DM/2, DM, DM, nullptr, hbuf);

  // LN2 + d_out prefill (h + b2)
  ln2_kernel<<<MROWS, blk256, 0, stream>>>(hbuf, ln2g, ln2b, xn, (float*)d_out, b2);

  transpose_kernel<<<dim3(DFF/32, DM/32), tb, 0, stream>>>(w1, wt, DM, DFF);
  gemm_kernel<EP_FFN1><<<dim3(MROWS/256, DFF/256, 1), blk512, 0, stream>>>(
      xn, wt, DM, DM, DFF, b1, a1);

  transpose_kernel<<<dim3(DM/32, DFF/32), tb, 0, stream>>>(w2, wt, DFF, DM);
  // FFN2: split-K=2 atomic accumulate into prefilled d_out
  gemm_kernel<EP_ATOMIC><<<dim3(MROWS/256, DM/256, 2), blk512, 0, stream>>>(
      a1, wt, DFF/2, DFF, DM, nullptr, (float*)d_out);
}

// Round 9
// 698.744 us; speedup vs baseline: 1.0883x; 1.0883x over previous
//
#include <hip/hip_runtime.h>
#include <math.h>

#define DM   2048
#define DFF  8192
#define NH   16
#define HD   128
#define SEQ  2048
#define MROWS 4096   // BATCH * SEQ

typedef __attribute__((ext_vector_type(4))) float  f32x4;
typedef __attribute__((ext_vector_type(8))) __bf16 bf16x8;
typedef __attribute__((ext_vector_type(4))) short  short4_t;

#define VMCNT(n) asm volatile("s_waitcnt vmcnt(" #n ")" ::: "memory")
#define LGKM0()  asm volatile("s_waitcnt lgkmcnt(0)" ::: "memory")
#define SBAR()   asm volatile("s_barrier" ::: "memory")

__device__ inline unsigned short f2bf(float f) {
  union { float f; unsigned int u; } x; x.f = f;
  unsigned int r = x.u + 0x7FFFu + ((x.u >> 16) & 1u);
  return (unsigned short)(r >> 16);
}

__device__ inline void gload16(const void* g, void* l) {
  __builtin_amdgcn_global_load_lds(
      (const __attribute__((address_space(1))) unsigned int*)g,
      (__attribute__((address_space(3))) unsigned int*)l, 16, 0, 0);
}

// ---------------- LayerNorm (f32 in, bf16 out) ----------------
__global__ __launch_bounds__(256) void ln_kernel(
    const float* __restrict__ in, const float* __restrict__ gw,
    const float* __restrict__ bw, unsigned short* __restrict__ out)
{
  const int row = blockIdx.x;
  const float* xr = in + (size_t)row * DM;
  const int t = threadIdx.x, lane = t & 63, w = t >> 6;
  float4 v0 = ((const float4*)xr)[t];
  float4 v1 = ((const float4*)xr)[t + 256];
  float s = v0.x+v0.y+v0.z+v0.w + v1.x+v1.y+v1.z+v1.w;
  float s2 = v0.x*v0.x+v0.y*v0.y+v0.z*v0.z+v0.w*v0.w
           + v1.x*v1.x+v1.y*v1.y+v1.z*v1.z+v1.w*v1.w;
  #pragma unroll
  for (int off = 32; off; off >>= 1) { s += __shfl_xor(s, off); s2 += __shfl_xor(s2, off); }
  __shared__ float rs[4], rs2[4];
  if (lane == 0) { rs[w] = s; rs2[w] = s2; }
  __syncthreads();
  s = rs[0] + rs[1] + rs[2] + rs[3];
  s2 = rs2[0] + rs2[1] + rs2[2] + rs2[3];
  const float mu = s * (1.0f / DM);
  const float var = s2 * (1.0f / DM) - mu * mu;
  const float rstd = rsqrtf(var + 1e-5f);
  float4 g0 = ((const float4*)gw)[t],     b0 = ((const float4*)bw)[t];
  float4 g1 = ((const float4*)gw)[t+256], b1 = ((const float4*)bw)[t+256];
  unsigned short* o = out + (size_t)row * DM;
  int i0 = t * 4, i1 = (t + 256) * 4;
  o[i0+0] = f2bf((v0.x-mu)*rstd*g0.x + b0.x);
  o[i0+1] = f2bf((v0.y-mu)*rstd*g0.y + b0.y);
  o[i0+2] = f2bf((v0.z-mu)*rstd*g0.z + b0.z);
  o[i0+3] = f2bf((v0.w-mu)*rstd*g0.w + b0.w);
  o[i1+0] = f2bf((v1.x-mu)*rstd*g1.x + b1.x);
  o[i1+1] = f2bf((v1.y-mu)*rstd*g1.y + b1.y);
  o[i1+2] = f2bf((v1.z-mu)*rstd*g1.z + b1.z);
  o[i1+3] = f2bf((v1.w-mu)*rstd*g1.w + b1.w);
}

// ------- weight transpose + f32->bf16: in[nrows][ncols] -> out[ncols][nrows] -------
__global__ void transpose_kernel(const float* __restrict__ in,
                                 unsigned short* __restrict__ out,
                                 int nrows, int ncols)
{
  __shared__ float tile[32][33];
  const int bx = blockIdx.x * 32;
  const int by = blockIdx.y * 32;
  const int tx = threadIdx.x, ty = threadIdx.y;
  #pragma unroll
  for (int i = ty; i < 32; i += 8)
    tile[i][tx] = in[(size_t)(by + i) * ncols + bx + tx];
  __syncthreads();
  #pragma unroll
  for (int i = ty; i < 32; i += 8)
    out[(size_t)(bx + i) * nrows + by + tx] = f2bf(tile[tx][i]);
}

// ------- batched transpose of the 4 DM x DM weights into wt -------
__global__ void transpose4_kernel(const float* __restrict__ w0,
                                  const float* __restrict__ w1,
                                  const float* __restrict__ w2,
                                  const float* __restrict__ w3,
                                  unsigned short* __restrict__ out)
{
  __shared__ float tile[32][33];
  const float* srcs[4] = {w0, w1, w2, w3};
  const float* in = srcs[blockIdx.z];
  unsigned short* o = out + (size_t)blockIdx.z * DM * DM;
  const int bx = blockIdx.x * 32;
  const int by = blockIdx.y * 32;
  const int tx = threadIdx.x, ty = threadIdx.y;
  #pragma unroll
  for (int i = ty; i < 32; i += 8)
    tile[i][tx] = in[(size_t)(by + i) * DM + bx + tx];
  __syncthreads();
  #pragma unroll
  for (int i = ty; i < 32; i += 8)
    o[(size_t)(bx + i) * DM + by + tx] = f2bf(tile[tx][i]);
}

// ================= GEMM 256x256 (QKV / FFN1) =================
// BK=64, 8 waves (2Mx4N), per-wave 128x64. LDS 128KB dbuf, chunk-swizzled.
// 4 phases/K-tile x 16 MFMA. Compiler-managed fine lgkmcnt between reads and
// MFMA (reads are plain loads -> precise dataflow waits); LGKM0 moved to
// BEFORE the trailing barrier (cross-wave overwrite safety only).
// Counted vmcnt(6) once per K-tile; never drained in steady state.
enum { EPA_QKV = 0, EPA_FFN1 = 1 };

template <int MODE>
__global__ __launch_bounds__(512, 2) void gemm256_kernel(
    const unsigned short* __restrict__ A,
    const unsigned short* __restrict__ Bt,
    int K, int N,
    const float* __restrict__ bias,
    void* __restrict__ out)
{
  __shared__ unsigned short lds[2][32768];

  const int t = threadIdx.x;
  const int w = t >> 6, lane = t & 63;
  const int wm = w >> 2, wn = w & 3;
  const int c = lane & 15, g = lane >> 4;

  const long bm = (long)blockIdx.x * 256;
  const long bn = (long)blockIdx.y * 256;
  const int NT = K >> 6;
  const size_t ks = (size_t)K;

  const int tr  = t >> 3;
  const int tc8 = (t & 7) * 8;
  const int sch = ((t & 7) ^ (tr & 7)) * 8;

  auto stageA = [&](int T, int mh) {
    const int s = T & 1;
    const int r0 = mh * 64 + tr;
    gload16(A + (bm + r0) * ks + T * 64 + sch,       &lds[s][r0 * 64 + tc8]);
    gload16(A + (bm + r0 + 128) * ks + T * 64 + sch, &lds[s][(r0 + 128) * 64 + tc8]);
  };
  auto stageB = [&](int T, int nh) {
    const int s = T & 1;
    const int r0 = nh * 32 + (tr & 31) + (tr >> 5) * 64;
    gload16(Bt + (bn + r0) * ks + T * 64 + sch,       &lds[s][16384 + r0 * 64 + tc8]);
    gload16(Bt + (bn + r0 + 128) * ks + T * 64 + sch, &lds[s][16384 + (r0 + 128) * 64 + tc8]);
  };

  f32x4 acc[8][4];
  #pragma unroll
  for (int i = 0; i < 8; i++)
    #pragma unroll
    for (int j = 0; j < 4; j++) acc[i][j] = (f32x4){0.f, 0.f, 0.f, 0.f};

  const int xo0 = ((0 + g) ^ (c & 7)) * 8;
  const int xo1 = ((4 + g) ^ (c & 7)) * 8;
  const int abase = (wm * 128 + c) * 64;
  const int bbase = 16384 + (wn * 64 + c) * 64;

  stageA(0, 0); stageB(0, 0); stageA(0, 1); stageB(0, 1);
  stageA(1, 0); stageB(1, 0); stageA(1, 1);
  VMCNT(6);
  SBAR();

  bf16x8 a[4][2], b0[2][2], b1[2][2];

  for (int T = 0; T < NT; T++) {
    const unsigned short* Ls = lds[T & 1];

    // ---- phase 0: read A-mh0 + B-nh0; stage B1(T+1); MFMA (mh0,nh0)
    #pragma unroll
    for (int mf = 0; mf < 4; mf++) {
      a[mf][0] = *(const bf16x8*)&Ls[abase + mf * 1024 + xo0];
      a[mf][1] = *(const bf16x8*)&Ls[abase + mf * 1024 + xo1];
    }
    #pragma unroll
    for (int nf = 0; nf < 2; nf++) {
      b0[nf][0] = *(const bf16x8*)&Ls[bbase + nf * 1024 + xo0];
      b0[nf][1] = *(const bf16x8*)&Ls[bbase + nf * 1024 + xo1];
    }
    if (T + 1 < NT) stageB(T + 1, 1);
    SBAR();
    __builtin_amdgcn_s_setprio(1);
    #pragma unroll
    for (int kk = 0; kk < 2; kk++)
      #pragma unroll
      for (int mf = 0; mf < 4; mf++)
        #pragma unroll
        for (int nf = 0; nf < 2; nf++)
          acc[mf][nf] = __builtin_amdgcn_mfma_f32_16x16x32_bf16(a[mf][kk], b0[nf][kk], acc[mf][nf], 0, 0, 0);
    __builtin_amdgcn_s_setprio(0);
    LGKM0();
    SBAR();

    // ---- phase 1: read B-nh1; stage A0(T+2); MFMA (mh0,nh1)
    #pragma unroll
    for (int nf = 0; nf < 2; nf++) {
      b1[nf][0] = *(const bf16x8*)&Ls[bbase + 2048 + nf * 1024 + xo0];
      b1[nf][1] = *(const bf16x8*)&Ls[bbase + 2048 + nf * 1024 + xo1];
    }
    if (T + 2 < NT) stageA(T + 2, 0);
    SBAR();
    __builtin_amdgcn_s_setprio(1);
    #pragma unroll
    for (int kk = 0; kk < 2; kk++)
      #pragma unroll
      for (int mf = 0; mf < 4; mf++)
        #pragma unroll
        for (int nf = 0; nf < 2; nf++)
          acc[mf][2 + nf] = __builtin_amdgcn_mfma_f32_16x16x32_bf16(a[mf][kk], b1[nf][kk], acc[mf][2 + nf], 0, 0, 0);
    __builtin_amdgcn_s_setprio(0);
    LGKM0();
    SBAR();

    // ---- phase 2: read A-mh1; stage B0(T+2); MFMA (mh1,nh0)
    #pragma unroll
    for (int mf = 0; mf < 4; mf++) {
      a[mf][0] = *(const bf16x8*)&Ls[abase + 4096 + mf * 1024 + xo0];
      a[mf][1] = *(const bf16x8*)&Ls[abase + 4096 + mf * 1024 + xo1];
    }
    if (T + 2 < NT) stageB(T + 2, 0);
    SBAR();
    __builtin_amdgcn_s_setprio(1);
    #pragma unroll
    for (int kk = 0; kk < 2; kk++)
      #pragma unroll
      for (int mf = 0; mf < 4; mf++)
        #pragma unroll
        for (int nf = 0; nf < 2; nf++)
          acc[4 + mf][nf] = __builtin_amdgcn_mfma_f32_16x16x32_bf16(a[mf][kk], b0[nf][kk], acc[4 + mf][nf], 0, 0, 0);
    __builtin_amdgcn_s_setprio(0);
    LGKM0();
    SBAR();

    // ---- phase 3: stage A1(T+2); MFMA (mh1,nh1); counted boundary vmcnt
    if (T + 2 < NT) stageA(T + 2, 1);
    __builtin_amdgcn_s_setprio(1);
    #pragma unroll
    for (int kk = 0; kk < 2; kk++)
      #pragma unroll
      for (int mf = 0; mf < 4; mf++)
        #pragma unroll
        for (int nf = 0; nf < 2; nf++)
          acc[4 + mf][2 + nf] = __builtin_amdgcn_mfma_f32_16x16x32_bf16(a[mf][kk], b1[nf][kk], acc[4 + mf][2 + nf], 0, 0, 0);
    __builtin_amdgcn_s_setprio(0);
    if (T + 2 < NT) { VMCNT(6); } else { VMCNT(0); }
    SBAR();
  }

  // ---------------- epilogue ----------------
  #pragma unroll
  for (int mf = 0; mf < 8; mf++) {
    const long row0 = bm + wm * 128 + mf * 16 + g * 4;
    #pragma unroll
    for (int nf = 0; nf < 4; nf++) {
      const long col = bn + wn * 64 + nf * 16 + c;
      #pragma unroll
      for (int r = 0; r < 4; r++) {
        const long row = row0 + r;
        float v = acc[mf][nf][r];
        if constexpr (MODE == EPA_QKV) {
          const int slot = (int)(col >> 11);
          const long cc = col & 2047;
          const long hh = cc >> 7, dd = cc & 127;
          const long bb = row >> 11, ss = row & 2047;
          unsigned short* o = (unsigned short*)out;
          if (slot == 0)
            o[((bb * NH + hh) * SEQ + ss) * HD + dd] = f2bf(v * 0.08838834764831845f);
          else if (slot == 1)
            o[8388608 + ((bb * NH + hh) * SEQ + ss) * HD + dd] = f2bf(v);
          else
            o[16777216 + ((bb * NH + hh) * HD + dd) * SEQ + ss] = f2bf(v);
        } else { // EPA_FFN1
          float u = v + bias[col];
          float y = 0.7978845608028654f * (u + 0.044715f * u * u * u);
          float e = __expf(-2.0f * fabsf(y));
          float th = (1.0f - e) / (1.0f + e);
          th = (y < 0.0f) ? -th : th;
          ((unsigned short*)out)[row * (long)N + col] = f2bf(0.5f * u * (1.0f + th));
        }
      }
    }
  }
}

// ================= GEMM 128x256 (WO / FFN2) =================
// BK=64, 8 waves (2Mx4N), per-wave 64x64. LDS 96KB dbuf (2x{A,B0,B1}),
// 2 phases/K-tile x 16 MFMA, same waitcnt discipline as gemm256.
enum { EPB_WO = 0, EPB_FFN2 = 1 };

template <int MODE>
__global__ __launch_bounds__(512, 2) void gemm128_kernel(
    const unsigned short* __restrict__ A,
    const unsigned short* __restrict__ Bt,
    int K, int N,
    const float* __restrict__ res,
    const float* __restrict__ bias,
    void* __restrict__ out)
{
  __shared__ unsigned short lds[2][3][8192];   // [slot][A,B0,B1][128 x 64]

  const int t = threadIdx.x;
  const int w = t >> 6, lane = t & 63;
  const int wm = w >> 2, wn = w & 3;
  const int c = lane & 15, g = lane >> 4;
  const int l3 = lane >> 3, l7 = lane & 7;

  const long bm = (long)blockIdx.x * 128;
  const long bn = (long)blockIdx.y * 256;
  const int NT = K >> 6;
  const size_t Ksz = (size_t)K;

  const int scol = (l7 ^ l3) * 8;
  const int r0a = w * 16;

  auto stA = [&](int T) {
    unsigned short* d = &lds[T & 1][0][r0a * 64];
    #pragma unroll
    for (int j = 0; j < 2; j++)
      gload16(A + (bm + r0a + j * 8 + l3) * Ksz + T * 64 + scol, d + j * 512);
  };
  auto stB = [&](int T, int nh) {
    unsigned short* d = &lds[T & 1][1 + nh][r0a * 64];
    #pragma unroll
    for (int j = 0; j < 2; j++)
      gload16(Bt + (bn + nh * 128 + r0a + j * 8 + l3) * Ksz + T * 64 + scol, d + j * 512);
  };

  f32x4 acc[2][2][2][2];
  #pragma unroll
  for (int i = 0; i < 2; i++)
    #pragma unroll
    for (int jq = 0; jq < 2; jq++)
      #pragma unroll
      for (int m = 0; m < 2; m++)
        #pragma unroll
        for (int n = 0; n < 2; n++) acc[i][jq][m][n] = (f32x4){0.f, 0.f, 0.f, 0.f};

  stA(0); stB(0, 0); stB(0, 1);
  stA(1); stB(1, 0);
  VMCNT(4);
  SBAR();

  const int arow = (wm * 64 + c) * 64;
  const int brow = (wn * 32 + c) * 64;
  const int k0o = (g ^ (c & 7)) * 8;
  const int k1o = ((4 | g) ^ (c & 7)) * 8;

  for (int T = 0; T < NT; T++) {
    const unsigned short* LA  = lds[T & 1][0];
    const unsigned short* LB0 = lds[T & 1][1];
    const unsigned short* LB1 = lds[T & 1][2];
    bf16x8 a[2][2][2], b[2][2];

    // ---- phase 0: read A(all)+B0; stage B1(T+1); MFMA nh=0
    #pragma unroll
    for (int mh = 0; mh < 2; mh++)
      #pragma unroll
      for (int m = 0; m < 2; m++) {
        a[mh][m][0] = *(const bf16x8*)&LA[arow + mh * 2048 + m * 1024 + k0o];
        a[mh][m][1] = *(const bf16x8*)&LA[arow + mh * 2048 + m * 1024 + k1o];
      }
    #pragma unroll
    for (int n = 0; n < 2; n++) {
      b[n][0] = *(const bf16x8*)&LB0[brow + n * 1024 + k0o];
      b[n][1] = *(const bf16x8*)&LB0[brow + n * 1024 + k1o];
    }
    if (T + 1 < NT) stB(T + 1, 1);
    SBAR();
    __builtin_amdgcn_s_setprio(1);
    #pragma unroll
    for (int kk = 0; kk < 2; kk++)
      #pragma unroll
      for (int mh = 0; mh < 2; mh++)
        #pragma unroll
        for (int m = 0; m < 2; m++)
          #pragma unroll
          for (int n = 0; n < 2; n++)
            acc[mh][0][m][n] = __builtin_amdgcn_mfma_f32_16x16x32_bf16(a[mh][m][kk], b[n][kk], acc[mh][0][m][n], 0, 0, 0);
    __builtin_amdgcn_s_setprio(0);
    LGKM0();
    SBAR();

    // ---- phase 1: read B1; stage A(T+2)+B0(T+2); MFMA nh=1
    #pragma unroll
    for (int n = 0; n < 2; n++) {
      b[n][0] = *(const bf16x8*)&LB1[brow + n * 1024 + k0o];
      b[n][1] = *(const bf16x8*)&LB1[brow + n * 1024 + k1o];
    }
    if (T + 2 < NT) { stA(T + 2); stB(T + 2, 0); }
    SBAR();
    __builtin_amdgcn_s_setprio(1);
    #pragma unroll
    for (int kk = 0; kk < 2; kk++)
      #pragma unroll
      for (int mh = 0; mh < 2; mh++)
        #pragma unroll
        for (int m = 0; m < 2; m++)
          #pragma unroll
          for (int n = 0; n < 2; n++)
            acc[mh][1][m][n] = __builtin_amdgcn_mfma_f32_16x16x32_bf16(a[mh][m][kk], b[n][kk], acc[mh][1][m][n], 0, 0, 0);
    __builtin_amdgcn_s_setprio(0);
    LGKM0();
    if (T + 2 < NT) { VMCNT(4); } else { VMCNT(0); }
    SBAR();
  }

  // ---------------- epilogue ----------------
  #pragma unroll
  for (int mh = 0; mh < 2; mh++)
    #pragma unroll
    for (int nh = 0; nh < 2; nh++)
      #pragma unroll
      for (int m = 0; m < 2; m++)
        #pragma unroll
        for (int n = 0; n < 2; n++) {
          const long row0 = bm + wm * 64 + mh * 32 + m * 16 + g * 4;
          const long col  = bn + nh * 128 + wn * 32 + n * 16 + c;
          #pragma unroll
          for (int r = 0; r < 4; r++) {
            const long row = row0 + r;
            float v = acc[mh][nh][m][n][r];
            if constexpr (MODE == EPB_WO) {
              ((float*)out)[row * DM + col] = res[row * DM + col] + v;
            } else { // EPB_FFN2
              ((float*)out)[row * DM + col] = res[row * DM + col] + v + bias[col];
            }
          }
        }
}

// ---------------- Flash attention, causal + alibi, LDS-staged K/V ----------------
__global__ __launch_bounds__(256) void attn_kernel(
    const unsigned short* __restrict__ Q,
    const unsigned short* __restrict__ Kg,
    const unsigned short* __restrict__ Vt,
    const float* __restrict__ alibi,
    unsigned short* __restrict__ Out)
{
  __shared__ unsigned short lds[2][16384];   // 2 x (16KB K | 16KB V)

  const int bh = blockIdx.x;
  const int h = bh & (NH - 1);
  const int b = bh >> 4;
  const int j = blockIdx.y;
  const int t = threadIdx.x;
  const int w = t >> 6;
  const int lane = t & 63;
  const int c = lane & 15, g = lane >> 4;
  const int cx = (c & 7) << 4;

  const char* KpB = (const char*)(Kg + (size_t)bh * SEQ * HD);
  const char* VpB = (const char*)(Vt + (size_t)bh * SEQ * HD);
  const unsigned short* Qp = Q + (size_t)bh * SEQ * HD;
  const float* Ah = alibi + (size_t)h * SEQ * SEQ;

  #pragma unroll 1
  for (int half = 0; half < 2; half++) {
    const int cidx = half ? (31 - j) : j;
    const int nt = cidx + 1;
    const int qb = cidx * 64;
    const int q0 = qb + w * 16, qc = q0 + c;

    bf16x8 qf[4];
    #pragma unroll
    for (int dt = 0; dt < 4; dt++)
      qf[dt] = *(const bf16x8*)(Qp + (size_t)qc * HD + dt * 32 + g * 8);

    f32x4 oacc[8];
    #pragma unroll
    for (int d = 0; d < 8; d++) oacc[d] = (f32x4){0.f, 0.f, 0.f, 0.f};
    float m_run = -1e30f, s_run = 0.f;
    const float* Ap = Ah + (size_t)qc * SEQ;

    auto stage = [&](int tt, unsigned short* dst) {
      const size_t kvo = (size_t)tt * 64;
      #pragma unroll
      for (int k = 0; k < 8; k++) {
        const int o = w * 8192 + k * 1024 + lane * 16;
        if (w < 2) {
          const int so = o ^ (((o >> 8) & 7) << 4);
          gload16(KpB + kvo * 256 + so, dst + ((w * 8192 + k * 1024) >> 1));
        } else {
          const int o2 = o - 16384;
          const int d = o2 >> 7, win = o2 & 127;
          gload16(VpB + (size_t)d * 4096 + kvo * 2 + (win ^ ((d & 7) << 4)),
                  dst + ((w * 8192 + k * 1024) >> 1));
        }
      }
    };

    stage(0, lds[0]);
    __syncthreads();
    int buf = 0;

    for (int tt = 0; tt < nt; tt++) {
      if (tt + 1 < nt) stage(tt + 1, lds[buf ^ 1]);
      const unsigned short* LK = lds[buf];
      const unsigned short* LV = lds[buf] + 8192;
      const int kv0 = tt * 64;

      f32x4 sc[4];
      #pragma unroll
      for (int st = 0; st < 4; st++) sc[st] = (f32x4){0.f, 0.f, 0.f, 0.f};
      #pragma unroll
      for (int dt = 0; dt < 4; dt++)
        #pragma unroll
        for (int st = 0; st < 4; st++) {
          bf16x8 kf = *(const bf16x8*)&LK[(st * 4096 + c * 256 + ((dt * 64 + g * 16) ^ cx)) >> 1];
          sc[st] = __builtin_amdgcn_mfma_f32_16x16x32_bf16(kf, qf[dt], sc[st], 0, 0, 0);
        }

      float4 al[4];
      #pragma unroll
      for (int st = 0; st < 4; st++) al[st] = *(const float4*)(Ap + kv0 + st * 16 + g * 4);
      float scr[16];
      #pragma unroll
      for (int st = 0; st < 4; st++) {
        scr[st*4+0] = (kv0 + st*16 + g*4 + 0 > qc) ? -1e30f : sc[st][0] + al[st].x;
        scr[st*4+1] = (kv0 + st*16 + g*4 + 1 > qc) ? -1e30f : sc[st][1] + al[st].y;
        scr[st*4+2] = (kv0 + st*16 + g*4 + 2 > qc) ? -1e30f : sc[st][2] + al[st].z;
        scr[st*4+3] = (kv0 + st*16 + g*4 + 3 > qc) ? -1e30f : sc[st][3] + al[st].w;
      }

      float tm = scr[0];
      #pragma unroll
      for (int i = 1; i < 16; i++) tm = fmaxf(tm, scr[i]);
      tm = fmaxf(tm, __shfl_xor(tm, 16));
      tm = fmaxf(tm, __shfl_xor(tm, 32));
      const float m_new = fmaxf(m_run, tm);
      const float corr = __expf(m_run - m_new);
      float pv[16]; float ps = 0.f;
      #pragma unroll
      for (int i = 0; i < 16; i++) { pv[i] = __expf(scr[i] - m_new); ps += pv[i]; }
      ps += __shfl_xor(ps, 16);
      ps += __shfl_xor(ps, 32);
      s_run = s_run * corr + ps;
      m_run = m_new;

      short4_t pf[4];
      #pragma unroll
      for (int st = 0; st < 4; st++) {
        pf[st][0] = (short)f2bf(pv[st*4+0]); pf[st][1] = (short)f2bf(pv[st*4+1]);
        pf[st][2] = (short)f2bf(pv[st*4+2]); pf[st][3] = (short)f2bf(pv[st*4+3]);
      }

      float cf[4];
      #pragma unroll
      for (int r = 0; r < 4; r++) cf[r] = __shfl(corr, g * 4 + r);

      #pragma unroll
      for (int dt = 0; dt < 8; dt++) {
        f32x4 o = oacc[dt];
        o[0] *= cf[0]; o[1] *= cf[1]; o[2] *= cf[2]; o[3] *= cf[3];
        #pragma unroll
        for (int st = 0; st < 4; st++) {
          short4_t vf = *(const short4_t*)&LV[((dt * 16 + c) * 128 + ((st * 32 + g * 8) ^ cx)) >> 1];
          o = __builtin_amdgcn_mfma_f32_16x16x16bf16_1k(pf[st], vf, o, 0, 0, 0);
        }
        oacc[dt] = o;
      }

      __syncthreads();
      buf ^= 1;
    }

    float inv[4];
    #pragma unroll
    for (int r = 0; r < 4; r++) inv[r] = 1.0f / __shfl(s_run, g * 4 + r);
    #pragma unroll
    for (int dt = 0; dt < 8; dt++)
      #pragma unroll
      for (int r = 0; r < 4; r++)
        Out[(size_t)(b * SEQ + q0 + g * 4 + r) * DM + h * HD + dt * 16 + c] =
            f2bf(oacc[dt][r] * inv[r]);
  }
}

// ---------------- launch ----------------
extern "C" void kernel_launch(void* const* d_in, const int* in_sizes, int n_in,
                              void* d_out, int out_size, void* d_ws, size_t ws_size,
                              hipStream_t stream) {
  const float* x     = (const float*)d_in[0];
  const float* alibi = (const float*)d_in[1];
  const float* Wq    = (const float*)d_in[2];
  const float* Wk    = (const float*)d_in[3];
  const float* Wv    = (const float*)d_in[4];
  const float* Wo    = (const float*)d_in[5];
  const float* ln1g  = (const float*)d_in[6];
  const float* ln1b  = (const float*)d_in[7];
  const float* ln2g  = (const float*)d_in[8];
  const float* ln2b  = (const float*)d_in[9];
  const float* w1    = (const float*)d_in[10];
  const float* b1    = (const float*)d_in[11];
  const float* w2    = (const float*)d_in[12];
  const float* b2    = (const float*)d_in[13];

  char* ws = (char*)d_ws;
  float*          hbuf = (float*)(ws);                                // 32MB f32 h
  unsigned short* xn   = (unsigned short*)(ws + (32ull  << 20));      // 16MB bf16
  unsigned short* qb   = (unsigned short*)(ws + (48ull  << 20));      // Q|K|V 48MB
  unsigned short* kb   = (unsigned short*)(ws + (64ull  << 20));
  unsigned short* vt   = (unsigned short*)(ws + (80ull  << 20));
  unsigned short* ao   = (unsigned short*)(ws + (96ull  << 20));      // 16MB attn out
  unsigned short* wt   = (unsigned short*)(ws + (112ull << 20));      // 34MB weights
  unsigned short* a1   = (unsigned short*)(ws + (48ull  << 20));      // 64MB FFN1 out

  dim3 blk256(256);
  dim3 blk512(512);
  dim3 tb(32, 8);

  ln_kernel<<<MROWS, blk256, 0, stream>>>(x, ln1g, ln1b, xn);
  transpose4_kernel<<<dim3(DM/32, DM/32, 4), tb, 0, stream>>>(Wq, Wk, Wv, Wo, wt);

  // fused QKV: N=6144, epilogue routes by col>>11
  gemm256_kernel<EPA_QKV><<<dim3(MROWS/256, (3*DM)/256), blk512, 0, stream>>>(
      xn, wt, DM, 3*DM, nullptr, qb);

  attn_kernel<<<dim3(NH * 2, 16), blk256, 0, stream>>>(qb, kb, vt, alibi, ao);

  // WO: hbuf = x + ao @ Wo^T   (256 blocks)
  gemm128_kernel<EPB_WO><<<dim3(MROWS/128, DM/256), blk512, 0, stream>>>(
      ao, wt + 3ull * DM * DM, DM, DM, x, nullptr, hbuf);

  ln_kernel<<<MROWS, blk256, 0, stream>>>(hbuf, ln2g, ln2b, xn);

  transpose_kernel<<<dim3(DFF/32, DM/32), tb, 0, stream>>>(w1, wt, DM, DFF);
  gemm256_kernel<EPA_FFN1><<<dim3(MROWS/256, DFF/256), blk512, 0, stream>>>(
      xn, wt, DM, DFF, b1, a1);

  transpose_kernel<<<dim3(DM/32, DFF/32), tb, 0, stream>>>(w2, wt, DFF, DM);
  // FFN2: d_out = hbuf + a1 @ w2^T + b2   (256 blocks)
  gemm128_kernel<EPB_FFN2><<<dim3(MROWS/128, DM/256), blk512, 0, stream>>>(
      a1, wt, DFF, DM, hbuf, b2, (float*)d_out);
}

// Round 10
// 656.115 us; speedup vs baseline: 1.1591x; 1.0650x over previous
//
#include <hip/hip_runtime.h>
#include <math.h>

#define DM   2048
#define DFF  8192
#define NH   16
#define HD   128
#define SEQ  2048
#define MROWS 4096   // BATCH * SEQ

typedef __attribute__((ext_vector_type(4))) float  f32x4;
typedef __attribute__((ext_vector_type(8))) __bf16 bf16x8;
typedef __attribute__((ext_vector_type(4))) short  short4_t;

#define VMCNT(n) asm volatile("s_waitcnt vmcnt(" #n ")" ::: "memory")
#define LGKM0()  asm volatile("s_waitcnt lgkmcnt(0)" ::: "memory")
#define SBAR()   asm volatile("s_barrier" ::: "memory")

__device__ inline unsigned short f2bf(float f) {
  union { float f; unsigned int u; } x; x.f = f;
  unsigned int r = x.u + 0x7FFFu + ((x.u >> 16) & 1u);
  return (unsigned short)(r >> 16);
}

__device__ inline void gload16(const void* g, void* l) {
  __builtin_amdgcn_global_load_lds(
      (const __attribute__((address_space(1))) unsigned int*)g,
      (__attribute__((address_space(3))) unsigned int*)l, 16, 0, 0);
}

// ---------------- LayerNorm (f32 in, bf16 out) ----------------
__global__ __launch_bounds__(256) void ln_kernel(
    const float* __restrict__ in, const float* __restrict__ gw,
    const float* __restrict__ bw, unsigned short* __restrict__ out)
{
  const int row = blockIdx.x;
  const float* xr = in + (size_t)row * DM;
  const int t = threadIdx.x, lane = t & 63, w = t >> 6;
  float4 v0 = ((const float4*)xr)[t];
  float4 v1 = ((const float4*)xr)[t + 256];
  float s = v0.x+v0.y+v0.z+v0.w + v1.x+v1.y+v1.z+v1.w;
  float s2 = v0.x*v0.x+v0.y*v0.y+v0.z*v0.z+v0.w*v0.w
           + v1.x*v1.x+v1.y*v1.y+v1.z*v1.z+v1.w*v1.w;
  #pragma unroll
  for (int off = 32; off; off >>= 1) { s += __shfl_xor(s, off); s2 += __shfl_xor(s2, off); }
  __shared__ float rs[4], rs2[4];
  if (lane == 0) { rs[w] = s; rs2[w] = s2; }
  __syncthreads();
  s = rs[0] + rs[1] + rs[2] + rs[3];
  s2 = rs2[0] + rs2[1] + rs2[2] + rs2[3];
  const float mu = s * (1.0f / DM);
  const float var = s2 * (1.0f / DM) - mu * mu;
  const float rstd = rsqrtf(var + 1e-5f);
  float4 g0 = ((const float4*)gw)[t],     b0 = ((const float4*)bw)[t];
  float4 g1 = ((const float4*)gw)[t+256], b1 = ((const float4*)bw)[t+256];
  unsigned short* o = out + (size_t)row * DM;
  int i0 = t * 4, i1 = (t + 256) * 4;
  o[i0+0] = f2bf((v0.x-mu)*rstd*g0.x + b0.x);
  o[i0+1] = f2bf((v0.y-mu)*rstd*g0.y + b0.y);
  o[i0+2] = f2bf((v0.z-mu)*rstd*g0.z + b0.z);
  o[i0+3] = f2bf((v0.w-mu)*rstd*g0.w + b0.w);
  o[i1+0] = f2bf((v1.x-mu)*rstd*g1.x + b1.x);
  o[i1+1] = f2bf((v1.y-mu)*rstd*g1.y + b1.y);
  o[i1+2] = f2bf((v1.z-mu)*rstd*g1.z + b1.z);
  o[i1+3] = f2bf((v1.w-mu)*rstd*g1.w + b1.w);
}

// ------- weight transpose + f32->bf16: in[nrows][ncols] -> out[ncols][nrows] -------
__global__ void transpose_kernel(const float* __restrict__ in,
                                 unsigned short* __restrict__ out,
                                 int nrows, int ncols)
{
  __shared__ float tile[32][33];
  const int bx = blockIdx.x * 32;
  const int by = blockIdx.y * 32;
  const int tx = threadIdx.x, ty = threadIdx.y;
  #pragma unroll
  for (int i = ty; i < 32; i += 8)
    tile[i][tx] = in[(size_t)(by + i) * ncols + bx + tx];
  __syncthreads();
  #pragma unroll
  for (int i = ty; i < 32; i += 8)
    out[(size_t)(bx + i) * nrows + by + tx] = f2bf(tile[tx][i]);
}

// ------- batched transpose of the 4 DM x DM weights into wt -------
__global__ void transpose4_kernel(const float* __restrict__ w0,
                                  const float* __restrict__ w1,
                                  const float* __restrict__ w2,
                                  const float* __restrict__ w3,
                                  unsigned short* __restrict__ out)
{
  __shared__ float tile[32][33];
  const float* srcs[4] = {w0, w1, w2, w3};
  const float* in = srcs[blockIdx.z];
  unsigned short* o = out + (size_t)blockIdx.z * DM * DM;
  const int bx = blockIdx.x * 32;
  const int by = blockIdx.y * 32;
  const int tx = threadIdx.x, ty = threadIdx.y;
  #pragma unroll
  for (int i = ty; i < 32; i += 8)
    tile[i][tx] = in[(size_t)(by + i) * DM + bx + tx];
  __syncthreads();
  #pragma unroll
  for (int i = ty; i < 32; i += 8)
    o[(size_t)(bx + i) * DM + by + tx] = f2bf(tile[tx][i]);
}

// ================= GEMM 256x256 (QK / FFN1) =================
// BK=64, 8 waves (2Mx4N), per-wave 128x64, LDS 128KB dbuf, chunk-swizzled.
// K-loop unrolled 2 tiles/iteration with LITERAL slot (m201 fidelity): all LDS
// bases compile-time; scheduler can move work across the tile boundary.
// Counted vmcnt(6) once per K-tile (drains exactly the next tile's 4 regions).
enum { EPA_QK = 0, EPA_FFN1 = 1 };

#define MFMA16_256(MB_, BV_, NB_)                                                 \
    _Pragma("unroll")                                                             \
    for (int kk = 0; kk < 2; kk++)                                                \
      _Pragma("unroll")                                                           \
      for (int mf = 0; mf < 4; mf++)                                              \
        _Pragma("unroll")                                                         \
        for (int nf = 0; nf < 2; nf++)                                            \
          acc[(MB_) + mf][(NB_) + nf] = __builtin_amdgcn_mfma_f32_16x16x32_bf16(  \
              a[mf][kk], BV_[nf][kk], acc[(MB_) + mf][(NB_) + nf], 0, 0, 0);

#define G256_TILE(T_, S_)                                                         \
  {                                                                               \
    const unsigned short* Ls = lds[S_];                                           \
    _Pragma("unroll")                                                             \
    for (int mf = 0; mf < 4; mf++) {                                              \
      a[mf][0] = *(const bf16x8*)&Ls[abase + mf * 1024 + xo0];                    \
      a[mf][1] = *(const bf16x8*)&Ls[abase + mf * 1024 + xo1];                    \
    }                                                                             \
    _Pragma("unroll")                                                             \
    for (int nf = 0; nf < 2; nf++) {                                              \
      b0[nf][0] = *(const bf16x8*)&Ls[bbase + nf * 1024 + xo0];                   \
      b0[nf][1] = *(const bf16x8*)&Ls[bbase + nf * 1024 + xo1];                   \
    }                                                                             \
    if ((T_) + 1 < NT) stageB((T_) + 1, 1, (S_) ^ 1);                             \
    SBAR();                                                                       \
    __builtin_amdgcn_s_setprio(1);                                                \
    MFMA16_256(0, b0, 0);                                                         \
    __builtin_amdgcn_s_setprio(0);                                                \
    LGKM0();                                                                      \
    SBAR();                                                                       \
    _Pragma("unroll")                                                             \
    for (int nf = 0; nf < 2; nf++) {                                              \
      b1[nf][0] = *(const bf16x8*)&Ls[bbase + 2048 + nf * 1024 + xo0];            \
      b1[nf][1] = *(const bf16x8*)&Ls[bbase + 2048 + nf * 1024 + xo1];            \
    }                                                                             \
    if ((T_) + 2 < NT) stageA((T_) + 2, 0, S_);                                   \
    SBAR();                                                                       \
    __builtin_amdgcn_s_setprio(1);                                                \
    MFMA16_256(0, b1, 2);                                                         \
    __builtin_amdgcn_s_setprio(0);                                                \
    LGKM0();                                                                      \
    SBAR();                                                                       \
    _Pragma("unroll")                                                             \
    for (int mf = 0; mf < 4; mf++) {                                              \
      a[mf][0] = *(const bf16x8*)&Ls[abase + 4096 + mf * 1024 + xo0];             \
      a[mf][1] = *(const bf16x8*)&Ls[abase + 4096 + mf * 1024 + xo1];             \
    }                                                                             \
    if ((T_) + 2 < NT) stageB((T_) + 2, 0, S_);                                   \
    SBAR();                                                                       \
    __builtin_amdgcn_s_setprio(1);                                                \
    MFMA16_256(4, b0, 0);                                                         \
    __builtin_amdgcn_s_setprio(0);                                                \
    LGKM0();                                                                      \
    SBAR();                                                                       \
    if ((T_) + 2 < NT) stageA((T_) + 2, 1, S_);                                   \
    __builtin_amdgcn_s_setprio(1);                                                \
    MFMA16_256(4, b1, 2);                                                         \
    __builtin_amdgcn_s_setprio(0);                                                \
    if ((T_) + 2 < NT) { VMCNT(6); } else { VMCNT(0); }                           \
    SBAR();                                                                       \
  }

template <int MODE>
__global__ __launch_bounds__(512, 2) void gemm256_kernel(
    const unsigned short* __restrict__ A,
    const unsigned short* __restrict__ Bt,
    int K, int N,
    const float* __restrict__ bias,
    void* __restrict__ out)
{
  __shared__ unsigned short lds[2][32768];

  const int t = threadIdx.x;
  const int w = t >> 6, lane = t & 63;
  const int wm = w >> 2, wn = w & 3;
  const int c = lane & 15, g = lane >> 4;

  const long bm = (long)blockIdx.x * 256;
  const long bn = (long)blockIdx.y * 256;
  const int NT = K >> 6;
  const size_t ks = (size_t)K;

  const int tr  = t >> 3;
  const int tc8 = (t & 7) * 8;
  const int sch = ((t & 7) ^ (tr & 7)) * 8;

  auto stageA = [&](int T, int mh, int s) {
    const int r0 = mh * 64 + tr;
    gload16(A + (bm + r0) * ks + T * 64 + sch,       &lds[s][r0 * 64 + tc8]);
    gload16(A + (bm + r0 + 128) * ks + T * 64 + sch, &lds[s][(r0 + 128) * 64 + tc8]);
  };
  auto stageB = [&](int T, int nh, int s) {
    const int r0 = nh * 32 + (tr & 31) + (tr >> 5) * 64;
    gload16(Bt + (bn + r0) * ks + T * 64 + sch,       &lds[s][16384 + r0 * 64 + tc8]);
    gload16(Bt + (bn + r0 + 128) * ks + T * 64 + sch, &lds[s][16384 + (r0 + 128) * 64 + tc8]);
  };

  f32x4 acc[8][4];
  #pragma unroll
  for (int i = 0; i < 8; i++)
    #pragma unroll
    for (int j = 0; j < 4; j++) acc[i][j] = (f32x4){0.f, 0.f, 0.f, 0.f};

  const int xo0 = ((0 + g) ^ (c & 7)) * 8;
  const int xo1 = ((4 + g) ^ (c & 7)) * 8;
  const int abase = (wm * 128 + c) * 64;
  const int bbase = 16384 + (wn * 64 + c) * 64;

  stageA(0, 0, 0); stageB(0, 0, 0); stageA(0, 1, 0); stageB(0, 1, 0);
  stageA(1, 0, 1); stageB(1, 0, 1); stageA(1, 1, 1);
  VMCNT(6);
  SBAR();

  bf16x8 a[4][2], b0[2][2], b1[2][2];

  for (int T = 0; T < NT; T += 2) {
    G256_TILE(T, 0);
    G256_TILE(T + 1, 1);
  }

  // ---------------- epilogue ----------------
  #pragma unroll
  for (int mf = 0; mf < 8; mf++) {
    const long row0 = bm + wm * 128 + mf * 16 + g * 4;
    #pragma unroll
    for (int nf = 0; nf < 4; nf++) {
      const long col = bn + wn * 64 + nf * 16 + c;
      #pragma unroll
      for (int r = 0; r < 4; r++) {
        const long row = row0 + r;
        float v = acc[mf][nf][r];
        if constexpr (MODE == EPA_QK) {
          // col in [0,4096): slot 0 -> Q (scaled), slot 1 -> K; both [B,H,S,D]
          const int slot = (int)(col >> 11);
          const long cc = col & 2047;
          const long hh = cc >> 7, dd = cc & 127;
          const long bb = row >> 11, ss = row & 2047;
          unsigned short* o = (unsigned short*)out;
          if (slot == 0)
            o[((bb * NH + hh) * SEQ + ss) * HD + dd] = f2bf(v * 0.08838834764831845f);
          else
            o[8388608 + ((bb * NH + hh) * SEQ + ss) * HD + dd] = f2bf(v);
        } else { // EPA_FFN1: bias + tanh-GELU -> bf16
          float u = v + bias[col];
          float y = 0.7978845608028654f * (u + 0.044715f * u * u * u);
          float e = __expf(-2.0f * fabsf(y));
          float th = (1.0f - e) / (1.0f + e);
          th = (y < 0.0f) ? -th : th;
          ((unsigned short*)out)[row * (long)N + col] = f2bf(0.5f * u * (1.0f + th));
        }
      }
    }
  }
}

// ================= GEMM 128x256 (V / WO / FFN2) =================
// BK=64, 8 waves (2Mx4N), per-wave 64x64, LDS 96KB dbuf, 2 phases/K-tile,
// 2-tile unrolled loop with literal slot. Counted vmcnt(4) per K-tile.
enum { EPB_V = 0, EPB_WO = 1, EPB_FFN2 = 2 };

#define MFMA16_128(NH_)                                                           \
    _Pragma("unroll")                                                             \
    for (int kk = 0; kk < 2; kk++)                                                \
      _Pragma("unroll")                                                           \
      for (int mh = 0; mh < 2; mh++)                                              \
        _Pragma("unroll")                                                         \
        for (int m = 0; m < 2; m++)                                               \
          _Pragma("unroll")                                                       \
          for (int n = 0; n < 2; n++)                                             \
            acc[mh][NH_][m][n] = __builtin_amdgcn_mfma_f32_16x16x32_bf16(         \
                a[mh][m][kk], b[n][kk], acc[mh][NH_][m][n], 0, 0, 0);

#define G128_TILE(T_, S_)                                                         \
  {                                                                               \
    const unsigned short* LA  = lds[S_][0];                                       \
    const unsigned short* LB0 = lds[S_][1];                                       \
    const unsigned short* LB1 = lds[S_][2];                                       \
    _Pragma("unroll")                                                             \
    for (int mh = 0; mh < 2; mh++)                                                \
      _Pragma("unroll")                                                           \
      for (int m = 0; m < 2; m++) {                                               \
        a[mh][m][0] = *(const bf16x8*)&LA[arow + mh * 2048 + m * 1024 + k0o];     \
        a[mh][m][1] = *(const bf16x8*)&LA[arow + mh * 2048 + m * 1024 + k1o];     \
      }                                                                           \
    _Pragma("unroll")                                                             \
    for (int n = 0; n < 2; n++) {                                                 \
      b[n][0] = *(const bf16x8*)&LB0[brow + n * 1024 + k0o];                      \
      b[n][1] = *(const bf16x8*)&LB0[brow + n * 1024 + k1o];                      \
    }                                                                             \
    if ((T_) + 1 < NT) stB((T_) + 1, 1, (S_) ^ 1);                                \
    SBAR();                                                                       \
    __builtin_amdgcn_s_setprio(1);                                                \
    MFMA16_128(0);                                                                \
    __builtin_amdgcn_s_setprio(0);                                                \
    LGKM0();                                                                      \
    SBAR();                                                                       \
    _Pragma("unroll")                                                             \
    for (int n = 0; n < 2; n++) {                                                 \
      b[n][0] = *(const bf16x8*)&LB1[brow + n * 1024 + k0o];                      \
      b[n][1] = *(const bf16x8*)&LB1[brow + n * 1024 + k1o];                      \
    }                                                                             \
    if ((T_) + 2 < NT) { stA((T_) + 2, S_); stB((T_) + 2, 0, S_); }               \
    SBAR();                                                                       \
    __builtin_amdgcn_s_setprio(1);                                                \
    MFMA16_128(1);                                                                \
    __builtin_amdgcn_s_setprio(0);                                                \
    LGKM0();                                                                      \
    if ((T_) + 2 < NT) { VMCNT(4); } else { VMCNT(0); }                           \
    SBAR();                                                                       \
  }

template <int MODE>
__global__ __launch_bounds__(512, 2) void gemm128_kernel(
    const unsigned short* __restrict__ A,
    const unsigned short* __restrict__ Bt,
    int K, int N,
    const float* __restrict__ res,
    const float* __restrict__ bias,
    void* __restrict__ out)
{
  __shared__ unsigned short lds[2][3][8192];   // [slot][A,B0,B1][128 x 64]

  const int t = threadIdx.x;
  const int w = t >> 6, lane = t & 63;
  const int wm = w >> 2, wn = w & 3;
  const int c = lane & 15, g = lane >> 4;
  const int l3 = lane >> 3, l7 = lane & 7;

  const long bm = (long)blockIdx.x * 128;
  const long bn = (long)blockIdx.y * 256;
  const int NT = K >> 6;
  const size_t Ksz = (size_t)K;

  const int scol = (l7 ^ l3) * 8;
  const int r0a = w * 16;

  auto stA = [&](int T, int s) {
    unsigned short* d = &lds[s][0][r0a * 64];
    #pragma unroll
    for (int j = 0; j < 2; j++)
      gload16(A + (bm + r0a + j * 8 + l3) * Ksz + T * 64 + scol, d + j * 512);
  };
  auto stB = [&](int T, int nh, int s) {
    unsigned short* d = &lds[s][1 + nh][r0a * 64];
    #pragma unroll
    for (int j = 0; j < 2; j++)
      gload16(Bt + (bn + nh * 128 + r0a + j * 8 + l3) * Ksz + T * 64 + scol, d + j * 512);
  };

  f32x4 acc[2][2][2][2];
  #pragma unroll
  for (int i = 0; i < 2; i++)
    #pragma unroll
    for (int jq = 0; jq < 2; jq++)
      #pragma unroll
      for (int m = 0; m < 2; m++)
        #pragma unroll
        for (int n = 0; n < 2; n++) acc[i][jq][m][n] = (f32x4){0.f, 0.f, 0.f, 0.f};

  stA(0, 0); stB(0, 0, 0); stB(0, 1, 0);
  stA(1, 1); stB(1, 0, 1);
  VMCNT(4);
  SBAR();

  const int arow = (wm * 64 + c) * 64;
  const int brow = (wn * 32 + c) * 64;
  const int k0o = (g ^ (c & 7)) * 8;
  const int k1o = ((4 | g) ^ (c & 7)) * 8;

  bf16x8 a[2][2][2], b[2][2];

  for (int T = 0; T < NT; T += 2) {
    G128_TILE(T, 0);
    G128_TILE(T + 1, 1);
  }

  // ---------------- epilogue ----------------
  #pragma unroll
  for (int mh = 0; mh < 2; mh++)
    #pragma unroll
    for (int nh = 0; nh < 2; nh++)
      #pragma unroll
      for (int m = 0; m < 2; m++)
        #pragma unroll
        for (int n = 0; n < 2; n++) {
          const long row0 = bm + wm * 64 + mh * 32 + m * 16 + g * 4;
          const long col  = bn + nh * 128 + wn * 32 + n * 16 + c;
          #pragma unroll
          for (int r = 0; r < 4; r++) {
            const long row = row0 + r;
            float v = acc[mh][nh][m][n][r];
            if constexpr (MODE == EPB_V) {
              // V output scattered transposed to [B,H,D,S]
              const long hh = col >> 7, dd = col & 127;
              const long bb = row >> 11, ss = row & 2047;
              ((unsigned short*)out)[((bb * NH + hh) * HD + dd) * SEQ + ss] = f2bf(v);
            } else if constexpr (MODE == EPB_WO) {
              ((float*)out)[row * DM + col] = res[row * DM + col] + v;
            } else { // EPB_FFN2
              ((float*)out)[row * DM + col] = res[row * DM + col] + v + bias[col];
            }
          }
        }
}

// ---------------- Flash attention, causal + alibi, LDS-staged K/V ----------------
__global__ __launch_bounds__(256) void attn_kernel(
    const unsigned short* __restrict__ Q,
    const unsigned short* __restrict__ Kg,
    const unsigned short* __restrict__ Vt,
    const float* __restrict__ alibi,
    unsigned short* __restrict__ Out)
{
  __shared__ unsigned short lds[2][16384];   // 2 x (16KB K | 16KB V)

  const int bh = blockIdx.x;
  const int h = bh & (NH - 1);
  const int b = bh >> 4;
  const int j = blockIdx.y;
  const int t = threadIdx.x;
  const int w = t >> 6;
  const int lane = t & 63;
  const int c = lane & 15, g = lane >> 4;
  const int cx = (c & 7) << 4;

  const char* KpB = (const char*)(Kg + (size_t)bh * SEQ * HD);
  const char* VpB = (const char*)(Vt + (size_t)bh * SEQ * HD);
  const unsigned short* Qp = Q + (size_t)bh * SEQ * HD;
  const float* Ah = alibi + (size_t)h * SEQ * SEQ;

  #pragma unroll 1
  for (int half = 0; half < 2; half++) {
    const int cidx = half ? (31 - j) : j;
    const int nt = cidx + 1;
    const int qb = cidx * 64;
    const int q0 = qb + w * 16, qc = q0 + c;

    bf16x8 qf[4];
    #pragma unroll
    for (int dt = 0; dt < 4; dt++)
      qf[dt] = *(const bf16x8*)(Qp + (size_t)qc * HD + dt * 32 + g * 8);

    f32x4 oacc[8];
    #pragma unroll
    for (int d = 0; d < 8; d++) oacc[d] = (f32x4){0.f, 0.f, 0.f, 0.f};
    float m_run = -1e30f, s_run = 0.f;
    const float* Ap = Ah + (size_t)qc * SEQ;

    auto stage = [&](int tt, unsigned short* dst) {
      const size_t kvo = (size_t)tt * 64;
      #pragma unroll
      for (int k = 0; k < 8; k++) {
        const int o = w * 8192 + k * 1024 + lane * 16;
        if (w < 2) {
          const int so = o ^ (((o >> 8) & 7) << 4);
          gload16(KpB + kvo * 256 + so, dst + ((w * 8192 + k * 1024) >> 1));
        } else {
          const int o2 = o - 16384;
          const int d = o2 >> 7, win = o2 & 127;
          gload16(VpB + (size_t)d * 4096 + kvo * 2 + (win ^ ((d & 7) << 4)),
                  dst + ((w * 8192 + k * 1024) >> 1));
        }
      }
    };

    stage(0, lds[0]);
    __syncthreads();
    int buf = 0;

    for (int tt = 0; tt < nt; tt++) {
      if (tt + 1 < nt) stage(tt + 1, lds[buf ^ 1]);
      const unsigned short* LK = lds[buf];
      const unsigned short* LV = lds[buf] + 8192;
      const int kv0 = tt * 64;

      f32x4 sc[4];
      #pragma unroll
      for (int st = 0; st < 4; st++) sc[st] = (f32x4){0.f, 0.f, 0.f, 0.f};
      #pragma unroll
      for (int dt = 0; dt < 4; dt++)
        #pragma unroll
        for (int st = 0; st < 4; st++) {
          bf16x8 kf = *(const bf16x8*)&LK[(st * 4096 + c * 256 + ((dt * 64 + g * 16) ^ cx)) >> 1];
          sc[st] = __builtin_amdgcn_mfma_f32_16x16x32_bf16(kf, qf[dt], sc[st], 0, 0, 0);
        }

      float4 al[4];
      #pragma unroll
      for (int st = 0; st < 4; st++) al[st] = *(const float4*)(Ap + kv0 + st * 16 + g * 4);
      float scr[16];
      #pragma unroll
      for (int st = 0; st < 4; st++) {
        scr[st*4+0] = (kv0 + st*16 + g*4 + 0 > qc) ? -1e30f : sc[st][0] + al[st].x;
        scr[st*4+1] = (kv0 + st*16 + g*4 + 1 > qc) ? -1e30f : sc[st][1] + al[st].y;
        scr[st*4+2] = (kv0 + st*16 + g*4 + 2 > qc) ? -1e30f : sc[st][2] + al[st].z;
        scr[st*4+3] = (kv0 + st*16 + g*4 + 3 > qc) ? -1e30f : sc[st][3] + al[st].w;
      }

      float tm = scr[0];
      #pragma unroll
      for (int i = 1; i < 16; i++) tm = fmaxf(tm, scr[i]);
      tm = fmaxf(tm, __shfl_xor(tm, 16));
      tm = fmaxf(tm, __shfl_xor(tm, 32));
      const float m_new = fmaxf(m_run, tm);
      const float corr = __expf(m_run - m_new);
      float pv[16]; float ps = 0.f;
      #pragma unroll
      for (int i = 0; i < 16; i++) { pv[i] = __expf(scr[i] - m_new); ps += pv[i]; }
      ps += __shfl_xor(ps, 16);
      ps += __shfl_xor(ps, 32);
      s_run = s_run * corr + ps;
      m_run = m_new;

      short4_t pf[4];
      #pragma unroll
      for (int st = 0; st < 4; st++) {
        pf[st][0] = (short)f2bf(pv[st*4+0]); pf[st][1] = (short)f2bf(pv[st*4+1]);
        pf[st][2] = (short)f2bf(pv[st*4+2]); pf[st][3] = (short)f2bf(pv[st*4+3]);
      }

      float cf[4];
      #pragma unroll
      for (int r = 0; r < 4; r++) cf[r] = __shfl(corr, g * 4 + r);

      #pragma unroll
      for (int dt = 0; dt < 8; dt++) {
        f32x4 o = oacc[dt];
        o[0] *= cf[0]; o[1] *= cf[1]; o[2] *= cf[2]; o[3] *= cf[3];
        #pragma unroll
        for (int st = 0; st < 4; st++) {
          short4_t vf = *(const short4_t*)&LV[((dt * 16 + c) * 128 + ((st * 32 + g * 8) ^ cx)) >> 1];
          o = __builtin_amdgcn_mfma_f32_16x16x16bf16_1k(pf[st], vf, o, 0, 0, 0);
        }
        oacc[dt] = o;
      }

      __syncthreads();
      buf ^= 1;
    }

    float inv[4];
    #pragma unroll
    for (int r = 0; r < 4; r++) inv[r] = 1.0f / __shfl(s_run, g * 4 + r);
    #pragma unroll
    for (int dt = 0; dt < 8; dt++)
      #pragma unroll
      for (int r = 0; r < 4; r++)
        Out[(size_t)(b * SEQ + q0 + g * 4 + r) * DM + h * HD + dt * 16 + c] =
            f2bf(oacc[dt][r] * inv[r]);
  }
}

// ---------------- launch ----------------
extern "C" void kernel_launch(void* const* d_in, const int* in_sizes, int n_in,
                              void* d_out, int out_size, void* d_ws, size_t ws_size,
                              hipStream_t stream) {
  const float* x     = (const float*)d_in[0];
  const float* alibi = (const float*)d_in[1];
  const float* Wq    = (const float*)d_in[2];
  const float* Wk    = (const float*)d_in[3];
  const float* Wv    = (const float*)d_in[4];
  const float* Wo    = (const float*)d_in[5];
  const float* ln1g  = (const float*)d_in[6];
  const float* ln1b  = (const float*)d_in[7];
  const float* ln2g  = (const float*)d_in[8];
  const float* ln2b  = (const float*)d_in[9];
  const float* w1    = (const float*)d_in[10];
  const float* b1    = (const float*)d_in[11];
  const float* w2    = (const float*)d_in[12];
  const float* b2    = (const float*)d_in[13];

  char* ws = (char*)d_ws;
  float*          hbuf = (float*)(ws);                                // 32MB f32 h
  unsigned short* xn   = (unsigned short*)(ws + (32ull  << 20));      // 16MB bf16
  unsigned short* qb   = (unsigned short*)(ws + (48ull  << 20));      // Q|K 32MB
  unsigned short* kb   = (unsigned short*)(ws + (64ull  << 20));
  unsigned short* vt   = (unsigned short*)(ws + (80ull  << 20));      // V^T 16MB
  unsigned short* ao   = (unsigned short*)(ws + (96ull  << 20));      // 16MB attn out
  unsigned short* wt   = (unsigned short*)(ws + (112ull << 20));      // 34MB weights
  unsigned short* a1   = (unsigned short*)(ws + (48ull  << 20));      // 64MB FFN1 out

  dim3 blk256(256);
  dim3 blk512(512);
  dim3 tb(32, 8);

  ln_kernel<<<MROWS, blk256, 0, stream>>>(x, ln1g, ln1b, xn);
  transpose4_kernel<<<dim3(DM/32, DM/32, 4), tb, 0, stream>>>(Wq, Wk, Wv, Wo, wt);

  // QK fused: N=4096, 256 blocks (exact round)
  gemm256_kernel<EPA_QK><<<dim3(MROWS/256, (2*DM)/256), blk512, 0, stream>>>(
      xn, wt, DM, 2*DM, nullptr, qb);
  // V: N=2048, 256 blocks (exact round), transposed epilogue
  gemm128_kernel<EPB_V><<<dim3(MROWS/128, DM/256), blk512, 0, stream>>>(
      xn, wt + 2ull * DM * DM, DM, DM, nullptr, nullptr, vt);

  attn_kernel<<<dim3(NH * 2, 16), blk256, 0, stream>>>(qb, kb, vt, alibi, ao);

  // WO: hbuf = x + ao @ Wo^T   (256 blocks)
  gemm128_kernel<EPB_WO><<<dim3(MROWS/128, DM/256), blk512, 0, stream>>>(
      ao, wt + 3ull * DM * DM, DM, DM, x, nullptr, hbuf);

  ln_kernel<<<MROWS, blk256, 0, stream>>>(hbuf, ln2g, ln2b, xn);

  transpose_kernel<<<dim3(DFF/32, DM/32), tb, 0, stream>>>(w1, wt, DM, DFF);
  gemm256_kernel<EPA_FFN1><<<dim3(MROWS/256, DFF/256), blk512, 0, stream>>>(
      xn, wt, DM, DFF, b1, a1);

  transpose_kernel<<<dim3(DM/32, DFF/32), tb, 0, stream>>>(w2, wt, DFF, DM);
  // FFN2: d_out = hbuf + a1 @ w2^T + b2   (256 blocks)
  gemm128_kernel<EPB_FFN2><<<dim3(MROWS/128, DM/256), blk512, 0, stream>>>(
      a1, wt, DFF, DM, hbuf, b2, (float*)d_out);
}

// Round 11
// 653.487 us; speedup vs baseline: 1.1637x; 1.0040x over previous
//
#include <hip/hip_runtime.h>
#include <math.h>

#define DM   2048
#define DFF  8192
#define NH   16
#define HD   128
#define SEQ  2048
#define MROWS 4096   // BATCH * SEQ

typedef __attribute__((ext_vector_type(4))) float  f32x4;
typedef __attribute__((ext_vector_type(8))) __bf16 bf16x8;
typedef __attribute__((ext_vector_type(4))) short  short4_t;

#define VMCNT(n) asm volatile("s_waitcnt vmcnt(" #n ")" ::: "memory")
#define LGKM0()  asm volatile("s_waitcnt lgkmcnt(0)" ::: "memory")
#define SBAR()   asm volatile("s_barrier" ::: "memory")

__device__ inline unsigned short f2bf(float f) {
  union { float f; unsigned int u; } x; x.f = f;
  unsigned int r = x.u + 0x7FFFu + ((x.u >> 16) & 1u);
  return (unsigned short)(r >> 16);
}

__device__ inline void gload16(const void* g, void* l) {
  __builtin_amdgcn_global_load_lds(
      (const __attribute__((address_space(1))) unsigned int*)g,
      (__attribute__((address_space(3))) unsigned int*)l, 16, 0, 0);
}

// ---------------- LayerNorm (f32 in, bf16 out) ----------------
__global__ __launch_bounds__(256) void ln_kernel(
    const float* __restrict__ in, const float* __restrict__ gw,
    const float* __restrict__ bw, unsigned short* __restrict__ out)
{
  const int row = blockIdx.x;
  const float* xr = in + (size_t)row * DM;
  const int t = threadIdx.x, lane = t & 63, w = t >> 6;
  float4 v0 = ((const float4*)xr)[t];
  float4 v1 = ((const float4*)xr)[t + 256];
  float s = v0.x+v0.y+v0.z+v0.w + v1.x+v1.y+v1.z+v1.w;
  float s2 = v0.x*v0.x+v0.y*v0.y+v0.z*v0.z+v0.w*v0.w
           + v1.x*v1.x+v1.y*v1.y+v1.z*v1.z+v1.w*v1.w;
  #pragma unroll
  for (int off = 32; off; off >>= 1) { s += __shfl_xor(s, off); s2 += __shfl_xor(s2, off); }
  __shared__ float rs[4], rs2[4];
  if (lane == 0) { rs[w] = s; rs2[w] = s2; }
  __syncthreads();
  s = rs[0] + rs[1] + rs[2] + rs[3];
  s2 = rs2[0] + rs2[1] + rs2[2] + rs2[3];
  const float mu = s * (1.0f / DM);
  const float var = s2 * (1.0f / DM) - mu * mu;
  const float rstd = rsqrtf(var + 1e-5f);
  float4 g0 = ((const float4*)gw)[t],     b0 = ((const float4*)bw)[t];
  float4 g1 = ((const float4*)gw)[t+256], b1 = ((const float4*)bw)[t+256];
  unsigned short* o = out + (size_t)row * DM;
  int i0 = t * 4, i1 = (t + 256) * 4;
  o[i0+0] = f2bf((v0.x-mu)*rstd*g0.x + b0.x);
  o[i0+1] = f2bf((v0.y-mu)*rstd*g0.y + b0.y);
  o[i0+2] = f2bf((v0.z-mu)*rstd*g0.z + b0.z);
  o[i0+3] = f2bf((v0.w-mu)*rstd*g0.w + b0.w);
  o[i1+0] = f2bf((v1.x-mu)*rstd*g1.x + b1.x);
  o[i1+1] = f2bf((v1.y-mu)*rstd*g1.y + b1.y);
  o[i1+2] = f2bf((v1.z-mu)*rstd*g1.z + b1.z);
  o[i1+3] = f2bf((v1.w-mu)*rstd*g1.w + b1.w);
}

// ------- weight transpose + f32->bf16: in[nrows][ncols] -> out[ncols][nrows] -------
__global__ void transpose_kernel(const float* __restrict__ in,
                                 unsigned short* __restrict__ out,
                                 int nrows, int ncols)
{
  __shared__ float tile[32][33];
  const int bx = blockIdx.x * 32;
  const int by = blockIdx.y * 32;
  const int tx = threadIdx.x, ty = threadIdx.y;
  #pragma unroll
  for (int i = ty; i < 32; i += 8)
    tile[i][tx] = in[(size_t)(by + i) * ncols + bx + tx];
  __syncthreads();
  #pragma unroll
  for (int i = ty; i < 32; i += 8)
    out[(size_t)(bx + i) * nrows + by + tx] = f2bf(tile[tx][i]);
}

// ------- batched transpose of the 4 DM x DM weights into wt -------
__global__ void transpose4_kernel(const float* __restrict__ w0,
                                  const float* __restrict__ w1,
                                  const float* __restrict__ w2,
                                  const float* __restrict__ w3,
                                  unsigned short* __restrict__ out)
{
  __shared__ float tile[32][33];
  const float* srcs[4] = {w0, w1, w2, w3};
  const float* in = srcs[blockIdx.z];
  unsigned short* o = out + (size_t)blockIdx.z * DM * DM;
  const int bx = blockIdx.x * 32;
  const int by = blockIdx.y * 32;
  const int tx = threadIdx.x, ty = threadIdx.y;
  #pragma unroll
  for (int i = ty; i < 32; i += 8)
    tile[i][tx] = in[(size_t)(by + i) * DM + bx + tx];
  __syncthreads();
  #pragma unroll
  for (int i = ty; i < 32; i += 8)
    o[(size_t)(bx + i) * DM + by + tx] = f2bf(tile[tx][i]);
}

// ================= GEMM 256x256 (QK / FFN1) =================
// BK=64, 8 waves (2Mx4N), per-wave 128x64, LDS 128KB dbuf, chunk-swizzled.
// (kk,mh) quadrant order -> 8/4/8/4 ds_read per phase (m201's balance):
//   ph0 (kk0,mh0): read a-mh0-kk0(4) + b-kk0(4); stage A-mh1(T+1)->S^1
//   ph1 (kk0,mh1): read a-mh1-kk0(4);            stage B1(T+1)->S^1
//   ph2 (kk1,mh0): read a-mh0-kk1(4) + b-kk1(4); no stage
//   ph3 (kk1,mh1): read a-mh1-kk1(4);            stage A-mh0(T+2)+B0(T+2)->S
// Staging legality (LGKM0 at each phase end = read-complete fence):
//   S.A-mh0/S.B0 freed after ph2 -> staged T+2 at ph3 (live slot);
//   S^1.A-mh1 freed T-1.ph3, S^1.B1 freed T-1.ph2 -> staged 1-ahead.
// Boundary vmcnt(4): leaves exactly A-mh0/B0(T+2) in flight; never drains.
enum { EPA_QK = 0, EPA_FFN1 = 1 };

#define MFMA16Q(MB_)                                                              \
    _Pragma("unroll")                                                             \
    for (int mf = 0; mf < 4; mf++)                                                \
      _Pragma("unroll")                                                           \
      for (int nf = 0; nf < 4; nf++)                                              \
        acc[(MB_) + mf][nf] = __builtin_amdgcn_mfma_f32_16x16x32_bf16(            \
            a[mf], b[nf], acc[(MB_) + mf][nf], 0, 0, 0);

#define G256_TILE(T_, S_)                                                         \
  {                                                                               \
    const unsigned short* Ls = lds[S_];                                           \
    /* ---- ph0: kk0, mh0 ---- */                                                 \
    _Pragma("unroll")                                                             \
    for (int mf = 0; mf < 4; mf++)                                                \
      a[mf] = *(const bf16x8*)&Ls[abase + mf * 1024 + xo0];                       \
    _Pragma("unroll")                                                             \
    for (int nf = 0; nf < 4; nf++)                                                \
      b[nf] = *(const bf16x8*)&Ls[bbase + nf * 1024 + xo0];                       \
    if ((T_) + 1 < NT) stageA((T_) + 1, 1, (S_) ^ 1);                             \
    SBAR();                                                                       \
    __builtin_amdgcn_s_setprio(1);                                                \
    MFMA16Q(0);                                                                   \
    __builtin_amdgcn_s_setprio(0);                                                \
    LGKM0();                                                                      \
    SBAR();                                                                       \
    /* ---- ph1: kk0, mh1 ---- */                                                 \
    _Pragma("unroll")                                                             \
    for (int mf = 0; mf < 4; mf++)                                                \
      a[mf] = *(const bf16x8*)&Ls[abase + 4096 + mf * 1024 + xo0];                \
    if ((T_) + 1 < NT) stageB((T_) + 1, 1, (S_) ^ 1);                             \
    SBAR();                                                                       \
    __builtin_amdgcn_s_setprio(1);                                                \
    MFMA16Q(4);                                                                   \
    __builtin_amdgcn_s_setprio(0);                                                \
    LGKM0();                                                                      \
    SBAR();                                                                       \
    /* ---- ph2: kk1, mh0 ---- */                                                 \
    _Pragma("unroll")                                                             \
    for (int mf = 0; mf < 4; mf++)                                                \
      a[mf] = *(const bf16x8*)&Ls[abase + mf * 1024 + xo1];                       \
    _Pragma("unroll")                                                             \
    for (int nf = 0; nf < 4; nf++)                                                \
      b[nf] = *(const bf16x8*)&Ls[bbase + nf * 1024 + xo1];                       \
    SBAR();                                                                       \
    __builtin_amdgcn_s_setprio(1);                                                \
    MFMA16Q(0);                                                                   \
    __builtin_amdgcn_s_setprio(0);                                                \
    LGKM0();                                                                      \
    SBAR();                                                                       \
    /* ---- ph3: kk1, mh1 ---- */                                                 \
    _Pragma("unroll")                                                             \
    for (int mf = 0; mf < 4; mf++)                                                \
      a[mf] = *(const bf16x8*)&Ls[abase + 4096 + mf * 1024 + xo1];                \
    if ((T_) + 2 < NT) { stageA((T_) + 2, 0, S_); stageB((T_) + 2, 0, S_); }      \
    SBAR();                                                                       \
    __builtin_amdgcn_s_setprio(1);                                                \
    MFMA16Q(4);                                                                   \
    __builtin_amdgcn_s_setprio(0);                                                \
    LGKM0();                                                                      \
    if ((T_) + 2 < NT) { VMCNT(4); } else { VMCNT(0); }                           \
    SBAR();                                                                       \
  }

template <int MODE>
__global__ __launch_bounds__(512, 2) void gemm256_kernel(
    const unsigned short* __restrict__ A,
    const unsigned short* __restrict__ Bt,
    int K, int N,
    const float* __restrict__ bias,
    void* __restrict__ out)
{
  __shared__ unsigned short lds[2][32768];

  const int t = threadIdx.x;
  const int w = t >> 6, lane = t & 63;
  const int wm = w >> 2, wn = w & 3;
  const int c = lane & 15, g = lane >> 4;

  const long bm = (long)blockIdx.x * 256;
  const long bn = (long)blockIdx.y * 256;
  const int NT = K >> 6;
  const size_t ks = (size_t)K;

  const int tr  = t >> 3;
  const int tc8 = (t & 7) * 8;
  const int sch = ((t & 7) ^ (tr & 7)) * 8;

  auto stageA = [&](int T, int mh, int s) {
    const int r0 = mh * 64 + tr;
    gload16(A + (bm + r0) * ks + T * 64 + sch,       &lds[s][r0 * 64 + tc8]);
    gload16(A + (bm + r0 + 128) * ks + T * 64 + sch, &lds[s][(r0 + 128) * 64 + tc8]);
  };
  auto stageB = [&](int T, int nh, int s) {
    const int r0 = nh * 32 + (tr & 31) + (tr >> 5) * 64;
    gload16(Bt + (bn + r0) * ks + T * 64 + sch,       &lds[s][16384 + r0 * 64 + tc8]);
    gload16(Bt + (bn + r0 + 128) * ks + T * 64 + sch, &lds[s][16384 + (r0 + 128) * 64 + tc8]);
  };

  f32x4 acc[8][4];
  #pragma unroll
  for (int i = 0; i < 8; i++)
    #pragma unroll
    for (int j = 0; j < 4; j++) acc[i][j] = (f32x4){0.f, 0.f, 0.f, 0.f};

  const int xo0 = ((0 + g) ^ (c & 7)) * 8;
  const int xo1 = ((4 + g) ^ (c & 7)) * 8;
  const int abase = (wm * 128 + c) * 64;
  const int bbase = 16384 + (wn * 64 + c) * 64;

  // prologue: tile0 full (8 loads) + tile1 A-mh0,B0 (4 loads)
  stageA(0, 0, 0); stageB(0, 0, 0); stageA(0, 1, 0); stageB(0, 1, 0);
  stageA(1, 0, 1); stageB(1, 0, 1);
  VMCNT(4);
  SBAR();

  bf16x8 a[4], b[4];

  for (int T = 0; T < NT; T += 2) {
    G256_TILE(T, 0);
    G256_TILE(T + 1, 1);
  }

  // ---------------- epilogue ----------------
  #pragma unroll
  for (int mf = 0; mf < 8; mf++) {
    const long row0 = bm + wm * 128 + mf * 16 + g * 4;
    #pragma unroll
    for (int nf = 0; nf < 4; nf++) {
      const long col = bn + wn * 64 + nf * 16 + c;
      #pragma unroll
      for (int r = 0; r < 4; r++) {
        const long row = row0 + r;
        float v = acc[mf][nf][r];
        if constexpr (MODE == EPA_QK) {
          // col in [0,4096): slot 0 -> Q (scaled), slot 1 -> K; both [B,H,S,D]
          const int slot = (int)(col >> 11);
          const long cc = col & 2047;
          const long hh = cc >> 7, dd = cc & 127;
          const long bb = row >> 11, ss = row & 2047;
          unsigned short* o = (unsigned short*)out;
          if (slot == 0)
            o[((bb * NH + hh) * SEQ + ss) * HD + dd] = f2bf(v * 0.08838834764831845f);
          else
            o[8388608 + ((bb * NH + hh) * SEQ + ss) * HD + dd] = f2bf(v);
        } else { // EPA_FFN1: bias + tanh-GELU -> bf16
          float u = v + bias[col];
          float y = 0.7978845608028654f * (u + 0.044715f * u * u * u);
          float e = __expf(-2.0f * fabsf(y));
          float th = (1.0f - e) / (1.0f + e);
          th = (y < 0.0f) ? -th : th;
          ((unsigned short*)out)[row * (long)N + col] = f2bf(0.5f * u * (1.0f + th));
        }
      }
    }
  }
}

// ================= GEMM 128x256 (V / WO / FFN2) =================
// BK=64, 8 waves (2Mx4N), per-wave 64x64, LDS 96KB dbuf, 2 phases/K-tile,
// 2-tile unrolled loop with literal slot. Counted vmcnt(4) per K-tile.
enum { EPB_V = 0, EPB_WO = 1, EPB_FFN2 = 2 };

#define MFMA16_128(NH_)                                                           \
    _Pragma("unroll")                                                             \
    for (int kk = 0; kk < 2; kk++)                                                \
      _Pragma("unroll")                                                           \
      for (int mh = 0; mh < 2; mh++)                                              \
        _Pragma("unroll")                                                         \
        for (int m = 0; m < 2; m++)                                               \
          _Pragma("unroll")                                                       \
          for (int n = 0; n < 2; n++)                                             \
            acc[mh][NH_][m][n] = __builtin_amdgcn_mfma_f32_16x16x32_bf16(         \
                a[mh][m][kk], b[n][kk], acc[mh][NH_][m][n], 0, 0, 0);

#define G128_TILE(T_, S_)                                                         \
  {                                                                               \
    const unsigned short* LA  = lds[S_][0];                                       \
    const unsigned short* LB0 = lds[S_][1];                                       \
    const unsigned short* LB1 = lds[S_][2];                                       \
    _Pragma("unroll")                                                             \
    for (int mh = 0; mh < 2; mh++)                                                \
      _Pragma("unroll")                                                           \
      for (int m = 0; m < 2; m++) {                                               \
        a[mh][m][0] = *(const bf16x8*)&LA[arow + mh * 2048 + m * 1024 + k0o];     \
        a[mh][m][1] = *(const bf16x8*)&LA[arow + mh * 2048 + m * 1024 + k1o];     \
      }                                                                           \
    _Pragma("unroll")                                                             \
    for (int n = 0; n < 2; n++) {                                                 \
      b[n][0] = *(const bf16x8*)&LB0[brow + n * 1024 + k0o];                      \
      b[n][1] = *(const bf16x8*)&LB0[brow + n * 1024 + k1o];                      \
    }                                                                             \
    if ((T_) + 1 < NT) stB((T_) + 1, 1, (S_) ^ 1);                                \
    SBAR();                                                                       \
    __builtin_amdgcn_s_setprio(1);                                                \
    MFMA16_128(0);                                                                \
    __builtin_amdgcn_s_setprio(0);                                                \
    LGKM0();                                                                      \
    SBAR();                                                                       \
    _Pragma("unroll")                                                             \
    for (int n = 0; n < 2; n++) {                                                 \
      b[n][0] = *(const bf16x8*)&LB1[brow + n * 1024 + k0o];                      \
      b[n][1] = *(const bf16x8*)&LB1[brow + n * 1024 + k1o];                      \
    }                                                                             \
    if ((T_) + 2 < NT) { stA((T_) + 2, S_); stB((T_) + 2, 0, S_); }               \
    SBAR();                                                                       \
    __builtin_amdgcn_s_setprio(1);                                                \
    MFMA16_128(1);                                                                \
    __builtin_amdgcn_s_setprio(0);                                                \
    LGKM0();                                                                      \
    if ((T_) + 2 < NT) { VMCNT(4); } else { VMCNT(0); }                           \
    SBAR();                                                                       \
  }

template <int MODE>
__global__ __launch_bounds__(512, 2) void gemm128_kernel(
    const unsigned short* __restrict__ A,
    const unsigned short* __restrict__ Bt,
    int K, int N,
    const float* __restrict__ res,
    const float* __restrict__ bias,
    void* __restrict__ out)
{
  __shared__ unsigned short lds[2][3][8192];   // [slot][A,B0,B1][128 x 64]

  const int t = threadIdx.x;
  const int w = t >> 6, lane = t & 63;
  const int wm = w >> 2, wn = w & 3;
  const int c = lane & 15, g = lane >> 4;
  const int l3 = lane >> 3, l7 = lane & 7;

  const long bm = (long)blockIdx.x * 128;
  const long bn = (long)blockIdx.y * 256;
  const int NT = K >> 6;
  const size_t Ksz = (size_t)K;

  const int scol = (l7 ^ l3) * 8;
  const int r0a = w * 16;

  auto stA = [&](int T, int s) {
    unsigned short* d = &lds[s][0][r0a * 64];
    #pragma unroll
    for (int j = 0; j < 2; j++)
      gload16(A + (bm + r0a + j * 8 + l3) * Ksz + T * 64 + scol, d + j * 512);
  };
  auto stB = [&](int T, int nh, int s) {
    unsigned short* d = &lds[s][1 + nh][r0a * 64];
    #pragma unroll
    for (int j = 0; j < 2; j++)
      gload16(Bt + (bn + nh * 128 + r0a + j * 8 + l3) * Ksz + T * 64 + scol, d + j * 512);
  };

  f32x4 acc[2][2][2][2];
  #pragma unroll
  for (int i = 0; i < 2; i++)
    #pragma unroll
    for (int jq = 0; jq < 2; jq++)
      #pragma unroll
      for (int m = 0; m < 2; m++)
        #pragma unroll
        for (int n = 0; n < 2; n++) acc[i][jq][m][n] = (f32x4){0.f, 0.f, 0.f, 0.f};

  stA(0, 0); stB(0, 0, 0); stB(0, 1, 0);
  stA(1, 1); stB(1, 0, 1);
  VMCNT(4);
  SBAR();

  const int arow = (wm * 64 + c) * 64;
  const int brow = (wn * 32 + c) * 64;
  const int k0o = (g ^ (c & 7)) * 8;
  const int k1o = ((4 | g) ^ (c & 7)) * 8;

  bf16x8 a[2][2][2], b[2][2];

  for (int T = 0; T < NT; T += 2) {
    G128_TILE(T, 0);
    G128_TILE(T + 1, 1);
  }

  // ---------------- epilogue ----------------
  #pragma unroll
  for (int mh = 0; mh < 2; mh++)
    #pragma unroll
    for (int nh = 0; nh < 2; nh++)
      #pragma unroll
      for (int m = 0; m < 2; m++)
        #pragma unroll
        for (int n = 0; n < 2; n++) {
          const long row0 = bm + wm * 64 + mh * 32 + m * 16 + g * 4;
          const long col  = bn + nh * 128 + wn * 32 + n * 16 + c;
          #pragma unroll
          for (int r = 0; r < 4; r++) {
            const long row = row0 + r;
            float v = acc[mh][nh][m][n][r];
            if constexpr (MODE == EPB_V) {
              // V output scattered transposed to [B,H,D,S]
              const long hh = col >> 7, dd = col & 127;
              const long bb = row >> 11, ss = row & 2047;
              ((unsigned short*)out)[((bb * NH + hh) * HD + dd) * SEQ + ss] = f2bf(v);
            } else if constexpr (MODE == EPB_WO) {
              ((float*)out)[row * DM + col] = res[row * DM + col] + v;
            } else { // EPB_FFN2
              ((float*)out)[row * DM + col] = res[row * DM + col] + v + bias[col];
            }
          }
        }
}

// ---------------- Flash attention, causal + alibi, LDS-staged K/V ----------------
__global__ __launch_bounds__(256) void attn_kernel(
    const unsigned short* __restrict__ Q,
    const unsigned short* __restrict__ Kg,
    const unsigned short* __restrict__ Vt,
    const float* __restrict__ alibi,
    unsigned short* __restrict__ Out)
{
  __shared__ unsigned short lds[2][16384];   // 2 x (16KB K | 16KB V)

  const int bh = blockIdx.x;
  const int h = bh & (NH - 1);
  const int b = bh >> 4;
  const int j = blockIdx.y;
  const int t = threadIdx.x;
  const int w = t >> 6;
  const int lane = t & 63;
  const int c = lane & 15, g = lane >> 4;
  const int cx = (c & 7) << 4;

  const char* KpB = (const char*)(Kg + (size_t)bh * SEQ * HD);
  const char* VpB = (const char*)(Vt + (size_t)bh * SEQ * HD);
  const unsigned short* Qp = Q + (size_t)bh * SEQ * HD;
  const float* Ah = alibi + (size_t)h * SEQ * SEQ;

  #pragma unroll 1
  for (int half = 0; half < 2; half++) {
    const int cidx = half ? (31 - j) : j;
    const int nt = cidx + 1;
    const int qb = cidx * 64;
    const int q0 = qb + w * 16, qc = q0 + c;

    bf16x8 qf[4];
    #pragma unroll
    for (int dt = 0; dt < 4; dt++)
      qf[dt] = *(const bf16x8*)(Qp + (size_t)qc * HD + dt * 32 + g * 8);

    f32x4 oacc[8];
    #pragma unroll
    for (int d = 0; d < 8; d++) oacc[d] = (f32x4){0.f, 0.f, 0.f, 0.f};
    float m_run = -1e30f, s_run = 0.f;
    const float* Ap = Ah + (size_t)qc * SEQ;

    auto stage = [&](int tt, unsigned short* dst) {
      const size_t kvo = (size_t)tt * 64;
      #pragma unroll
      for (int k = 0; k < 8; k++) {
        const int o = w * 8192 + k * 1024 + lane * 16;
        if (w < 2) {
          const int so = o ^ (((o >> 8) & 7) << 4);
          gload16(KpB + kvo * 256 + so, dst + ((w * 8192 + k * 1024) >> 1));
        } else {
          const int o2 = o - 16384;
          const int d = o2 >> 7, win = o2 & 127;
          gload16(VpB + (size_t)d * 4096 + kvo * 2 + (win ^ ((d & 7) << 4)),
                  dst + ((w * 8192 + k * 1024) >> 1));
        }
      }
    };

    stage(0, lds[0]);
    __syncthreads();
    int buf = 0;

    for (int tt = 0; tt < nt; tt++) {
      if (tt + 1 < nt) stage(tt + 1, lds[buf ^ 1]);
      const unsigned short* LK = lds[buf];
      const unsigned short* LV = lds[buf] + 8192;
      const int kv0 = tt * 64;

      f32x4 sc[4];
      #pragma unroll
      for (int st = 0; st < 4; st++) sc[st] = (f32x4){0.f, 0.f, 0.f, 0.f};
      #pragma unroll
      for (int dt = 0; dt < 4; dt++)
        #pragma unroll
        for (int st = 0; st < 4; st++) {
          bf16x8 kf = *(const bf16x8*)&LK[(st * 4096 + c * 256 + ((dt * 64 + g * 16) ^ cx)) >> 1];
          sc[st] = __builtin_amdgcn_mfma_f32_16x16x32_bf16(kf, qf[dt], sc[st], 0, 0, 0);
        }

      float4 al[4];
      #pragma unroll
      for (int st = 0; st < 4; st++) al[st] = *(const float4*)(Ap + kv0 + st * 16 + g * 4);
      float scr[16];
      #pragma unroll
      for (int st = 0; st < 4; st++) {
        scr[st*4+0] = (kv0 + st*16 + g*4 + 0 > qc) ? -1e30f : sc[st][0] + al[st].x;
        scr[st*4+1] = (kv0 + st*16 + g*4 + 1 > qc) ? -1e30f : sc[st][1] + al[st].y;
        scr[st*4+2] = (kv0 + st*16 + g*4 + 2 > qc) ? -1e30f : sc[st][2] + al[st].z;
        scr[st*4+3] = (kv0 + st*16 + g*4 + 3 > qc) ? -1e30f : sc[st][3] + al[st].w;
      }

      float tm = scr[0];
      #pragma unroll
      for (int i = 1; i < 16; i++) tm = fmaxf(tm, scr[i]);
      tm = fmaxf(tm, __shfl_xor(tm, 16));
      tm = fmaxf(tm, __shfl_xor(tm, 32));
      const float m_new = fmaxf(m_run, tm);
      const float corr = __expf(m_run - m_new);
      float pv[16]; float ps = 0.f;
      #pragma unroll
      for (int i = 0; i < 16; i++) { pv[i] = __expf(scr[i] - m_new); ps += pv[i]; }
      ps += __shfl_xor(ps, 16);
      ps += __shfl_xor(ps, 32);
      s_run = s_run * corr + ps;
      m_run = m_new;

      short4_t pf[4];
      #pragma unroll
      for (int st = 0; st < 4; st++) {
        pf[st][0] = (short)f2bf(pv[st*4+0]); pf[st][1] = (short)f2bf(pv[st*4+1]);
        pf[st][2] = (short)f2bf(pv[st*4+2]); pf[st][3] = (short)f2bf(pv[st*4+3]);
      }

      float cf[4];
      #pragma unroll
      for (int r = 0; r < 4; r++) cf[r] = __shfl(corr, g * 4 + r);

      #pragma unroll
      for (int dt = 0; dt < 8; dt++) {
        f32x4 o = oacc[dt];
        o[0] *= cf[0]; o[1] *= cf[1]; o[2] *= cf[2]; o[3] *= cf[3];
        #pragma unroll
        for (int st = 0; st < 4; st++) {
          short4_t vf = *(const short4_t*)&LV[((dt * 16 + c) * 128 + ((st * 32 + g * 8) ^ cx)) >> 1];
          o = __builtin_amdgcn_mfma_f32_16x16x16bf16_1k(pf[st], vf, o, 0, 0, 0);
        }
        oacc[dt] = o;
      }

      __syncthreads();
      buf ^= 1;
    }

    float inv[4];
    #pragma unroll
    for (int r = 0; r < 4; r++) inv[r] = 1.0f / __shfl(s_run, g * 4 + r);
    #pragma unroll
    for (int dt = 0; dt < 8; dt++)
      #pragma unroll
      for (int r = 0; r < 4; r++)
        Out[(size_t)(b * SEQ + q0 + g * 4 + r) * DM + h * HD + dt * 16 + c] =
            f2bf(oacc[dt][r] * inv[r]);
  }
}

// ---------------- launch ----------------
extern "C" void kernel_launch(void* const* d_in, const int* in_sizes, int n_in,
                              void* d_out, int out_size, void* d_ws, size_t ws_size,
                              hipStream_t stream) {
  const float* x     = (const float*)d_in[0];
  const float* alibi = (const float*)d_in[1];
  const float* Wq    = (const float*)d_in[2];
  const float* Wk    = (const float*)d_in[3];
  const float* Wv    = (const float*)d_in[4];
  const float* Wo    = (const float*)d_in[5];
  const float* ln1g  = (const float*)d_in[6];
  const float* ln1b  = (const float*)d_in[7];
  const float* ln2g  = (const float*)d_in[8];
  const float* ln2b  = (const float*)d_in[9];
  const float* w1    = (const float*)d_in[10];
  const float* b1    = (const float*)d_in[11];
  const float* w2    = (const float*)d_in[12];
  const float* b2    = (const float*)d_in[13];

  char* ws = (char*)d_ws;
  float*          hbuf = (float*)(ws);                                // 32MB f32 h
  unsigned short* xn   = (unsigned short*)(ws + (32ull  << 20));      // 16MB bf16
  unsigned short* qb   = (unsigned short*)(ws + (48ull  << 20));      // Q|K 32MB
  unsigned short* kb   = (unsigned short*)(ws + (64ull  << 20));
  unsigned short* vt   = (unsigned short*)(ws + (80ull  << 20));      // V^T 16MB
  unsigned short* ao   = (unsigned short*)(ws + (96ull  << 20));      // 16MB attn out
  unsigned short* wt   = (unsigned short*)(ws + (112ull << 20));      // 34MB weights
  unsigned short* a1   = (unsigned short*)(ws + (48ull  << 20));      // 64MB FFN1 out

  dim3 blk256(256);
  dim3 blk512(512);
  dim3 tb(32, 8);

  ln_kernel<<<MROWS, blk256, 0, stream>>>(x, ln1g, ln1b, xn);
  transpose4_kernel<<<dim3(DM/32, DM/32, 4), tb, 0, stream>>>(Wq, Wk, Wv, Wo, wt);

  // QK fused: N=4096, 256 blocks (exact round)
  gemm256_kernel<EPA_QK><<<dim3(MROWS/256, (2*DM)/256), blk512, 0, stream>>>(
      xn, wt, DM, 2*DM, nullptr, qb);
  // V: N=2048, 256 blocks (exact round), transposed epilogue
  gemm128_kernel<EPB_V><<<dim3(MROWS/128, DM/256), blk512, 0, stream>>>(
      xn, wt + 2ull * DM * DM, DM, DM, nullptr, nullptr, vt);

  attn_kernel<<<dim3(NH * 2, 16), blk256, 0, stream>>>(qb, kb, vt, alibi, ao);

  // WO: hbuf = x + ao @ Wo^T   (256 blocks)
  gemm128_kernel<EPB_WO><<<dim3(MROWS/128, DM/256), blk512, 0, stream>>>(
      ao, wt + 3ull * DM * DM, DM, DM, x, nullptr, hbuf);

  ln_kernel<<<MROWS, blk256, 0, stream>>>(hbuf, ln2g, ln2b, xn);

  transpose_kernel<<<dim3(DFF/32, DM/32), tb, 0, stream>>>(w1, wt, DM, DFF);
  gemm256_kernel<EPA_FFN1><<<dim3(MROWS/256, DFF/256), blk512, 0, stream>>>(
      xn, wt, DM, DFF, b1, a1);

  transpose_kernel<<<dim3(DM/32, DFF/32), tb, 0, stream>>>(w2, wt, DFF, DM);
  // FFN2: d_out = hbuf + a1 @ w2^T + b2   (256 blocks)
  gemm128_kernel<EPB_FFN2><<<dim3(MROWS/128, DM/256), blk512, 0, stream>>>(
      a1, wt, DFF, DM, hbuf, b2, (float*)d_out);
}

// Round 12
// 637.804 us; speedup vs baseline: 1.1923x; 1.0246x over previous
//
#include <hip/hip_runtime.h>
#include <math.h>

#define DM   2048
#define DFF  8192
#define NH   16
#define HD   128
#define SEQ  2048
#define MROWS 4096   // BATCH * SEQ

typedef __attribute__((ext_vector_type(4))) float  f32x4;
typedef __attribute__((ext_vector_type(8))) __bf16 bf16x8;
typedef __attribute__((ext_vector_type(4))) short  short4_t;

#define VMCNT(n) asm volatile("s_waitcnt vmcnt(" #n ")" ::: "memory")
#define LGKM0()  asm volatile("s_waitcnt lgkmcnt(0)" ::: "memory")
#define SBAR()   asm volatile("s_barrier" ::: "memory")

__device__ inline unsigned short f2bf(float f) {
  union { float f; unsigned int u; } x; x.f = f;
  unsigned int r = x.u + 0x7FFFu + ((x.u >> 16) & 1u);
  return (unsigned short)(r >> 16);
}

__device__ inline void gload16(const void* g, void* l) {
  __builtin_amdgcn_global_load_lds(
      (const __attribute__((address_space(1))) unsigned int*)g,
      (__attribute__((address_space(3))) unsigned int*)l, 16, 0, 0);
}

// XCD-bijective block swizzle (valid because all our grids have nwg % 8 == 0)
__device__ inline int xcd_swz(int bid, int nwg) {
  return (bid & 7) * (nwg >> 3) + (bid >> 3);
}

// ---------------- LayerNorm (f32 in, bf16 out) ----------------
__global__ __launch_bounds__(256) void ln_kernel(
    const float* __restrict__ in, const float* __restrict__ gw,
    const float* __restrict__ bw, unsigned short* __restrict__ out)
{
  const int row = blockIdx.x;
  const float* xr = in + (size_t)row * DM;
  const int t = threadIdx.x, lane = t & 63, w = t >> 6;
  float4 v0 = ((const float4*)xr)[t];
  float4 v1 = ((const float4*)xr)[t + 256];
  float s = v0.x+v0.y+v0.z+v0.w + v1.x+v1.y+v1.z+v1.w;
  float s2 = v0.x*v0.x+v0.y*v0.y+v0.z*v0.z+v0.w*v0.w
           + v1.x*v1.x+v1.y*v1.y+v1.z*v1.z+v1.w*v1.w;
  #pragma unroll
  for (int off = 32; off; off >>= 1) { s += __shfl_xor(s, off); s2 += __shfl_xor(s2, off); }
  __shared__ float rs[4], rs2[4];
  if (lane == 0) { rs[w] = s; rs2[w] = s2; }
  __syncthreads();
  s = rs[0] + rs[1] + rs[2] + rs[3];
  s2 = rs2[0] + rs2[1] + rs2[2] + rs2[3];
  const float mu = s * (1.0f / DM);
  const float var = s2 * (1.0f / DM) - mu * mu;
  const float rstd = rsqrtf(var + 1e-5f);
  float4 g0 = ((const float4*)gw)[t],     b0 = ((const float4*)bw)[t];
  float4 g1 = ((const float4*)gw)[t+256], b1 = ((const float4*)bw)[t+256];
  unsigned short* o = out + (size_t)row * DM;
  int i0 = t * 4, i1 = (t + 256) * 4;
  o[i0+0] = f2bf((v0.x-mu)*rstd*g0.x + b0.x);
  o[i0+1] = f2bf((v0.y-mu)*rstd*g0.y + b0.y);
  o[i0+2] = f2bf((v0.z-mu)*rstd*g0.z + b0.z);
  o[i0+3] = f2bf((v0.w-mu)*rstd*g0.w + b0.w);
  o[i1+0] = f2bf((v1.x-mu)*rstd*g1.x + b1.x);
  o[i1+1] = f2bf((v1.y-mu)*rstd*g1.y + b1.y);
  o[i1+2] = f2bf((v1.z-mu)*rstd*g1.z + b1.z);
  o[i1+3] = f2bf((v1.w-mu)*rstd*g1.w + b1.w);
}

// ------- weight transpose + f32->bf16: in[nrows][ncols] -> out[ncols][nrows] -------
__global__ void transpose_kernel(const float* __restrict__ in,
                                 unsigned short* __restrict__ out,
                                 int nrows, int ncols)
{
  __shared__ float tile[32][33];
  const int bx = blockIdx.x * 32;
  const int by = blockIdx.y * 32;
  const int tx = threadIdx.x, ty = threadIdx.y;
  #pragma unroll
  for (int i = ty; i < 32; i += 8)
    tile[i][tx] = in[(size_t)(by + i) * ncols + bx + tx];
  __syncthreads();
  #pragma unroll
  for (int i = ty; i < 32; i += 8)
    out[(size_t)(bx + i) * nrows + by + tx] = f2bf(tile[tx][i]);
}

// ------- batched transpose of the 4 DM x DM weights into wt -------
__global__ void transpose4_kernel(const float* __restrict__ w0,
                                  const float* __restrict__ w1,
                                  const float* __restrict__ w2,
                                  const float* __restrict__ w3,
                                  unsigned short* __restrict__ out)
{
  __shared__ float tile[32][33];
  const float* srcs[4] = {w0, w1, w2, w3};
  const float* in = srcs[blockIdx.z];
  unsigned short* o = out + (size_t)blockIdx.z * DM * DM;
  const int bx = blockIdx.x * 32;
  const int by = blockIdx.y * 32;
  const int tx = threadIdx.x, ty = threadIdx.y;
  #pragma unroll
  for (int i = ty; i < 32; i += 8)
    tile[i][tx] = in[(size_t)(by + i) * DM + bx + tx];
  __syncthreads();
  #pragma unroll
  for (int i = ty; i < 32; i += 8)
    o[(size_t)(bx + i) * DM + by + tx] = f2bf(tile[tx][i]);
}

// ================= GEMM 256x256 (QK / FFN1) =================
// BK=64, 8 waves (2Mx4N), per-wave 128x64, LDS 128KB dbuf, chunk-swizzled.
// ONE barrier per phase (pre-MFMA barrier removed): each wave's MFMA depends
// only on its OWN ds_reads (compiler inserts precise lgkmcnt waits); stage
// legality uses only the phase-END LGKM0+SBAR seal (re-derived: every staged
// region's last reader is >=1 sealed phase earlier). Waves desync within a
// phase -> one wave's LDS-read burst overlaps another's MFMA burst; setprio(1)
// arbitrates toward MFMA. Counted vmcnt(4) once per K-tile (never drains).
enum { EPA_QK = 0, EPA_FFN1 = 1 };

#define MFMA16Q(MB_)                                                              \
    _Pragma("unroll")                                                             \
    for (int mf = 0; mf < 4; mf++)                                                \
      _Pragma("unroll")                                                           \
      for (int nf = 0; nf < 4; nf++)                                              \
        acc[(MB_) + mf][nf] = __builtin_amdgcn_mfma_f32_16x16x32_bf16(            \
            a[mf], b[nf], acc[(MB_) + mf][nf], 0, 0, 0);

#define G256_TILE(T_, S_)                                                         \
  {                                                                               \
    const unsigned short* Ls = lds[S_];                                           \
    /* ---- ph0: kk0, mh0 ---- */                                                 \
    _Pragma("unroll")                                                             \
    for (int mf = 0; mf < 4; mf++)                                                \
      a[mf] = *(const bf16x8*)&Ls[abase + mf * 1024 + xo0];                       \
    _Pragma("unroll")                                                             \
    for (int nf = 0; nf < 4; nf++)                                                \
      b[nf] = *(const bf16x8*)&Ls[bbase + nf * 1024 + xo0];                       \
    if ((T_) + 1 < NT) stageA((T_) + 1, 1, (S_) ^ 1);                             \
    __builtin_amdgcn_s_setprio(1);                                                \
    MFMA16Q(0);                                                                   \
    __builtin_amdgcn_s_setprio(0);                                                \
    LGKM0();                                                                      \
    SBAR();                                                                       \
    /* ---- ph1: kk0, mh1 ---- */                                                 \
    _Pragma("unroll")                                                             \
    for (int mf = 0; mf < 4; mf++)                                                \
      a[mf] = *(const bf16x8*)&Ls[abase + 4096 + mf * 1024 + xo0];                \
    if ((T_) + 1 < NT) stageB((T_) + 1, 1, (S_) ^ 1);                             \
    __builtin_amdgcn_s_setprio(1);                                                \
    MFMA16Q(4);                                                                   \
    __builtin_amdgcn_s_setprio(0);                                                \
    LGKM0();                                                                      \
    SBAR();                                                                       \
    /* ---- ph2: kk1, mh0 ---- */                                                 \
    _Pragma("unroll")                                                             \
    for (int mf = 0; mf < 4; mf++)                                                \
      a[mf] = *(const bf16x8*)&Ls[abase + mf * 1024 + xo1];                       \
    _Pragma("unroll")                                                             \
    for (int nf = 0; nf < 4; nf++)                                                \
      b[nf] = *(const bf16x8*)&Ls[bbase + nf * 1024 + xo1];                       \
    __builtin_amdgcn_s_setprio(1);                                                \
    MFMA16Q(0);                                                                   \
    __builtin_amdgcn_s_setprio(0);                                                \
    LGKM0();                                                                      \
    SBAR();                                                                       \
    /* ---- ph3: kk1, mh1 ---- */                                                 \
    _Pragma("unroll")                                                             \
    for (int mf = 0; mf < 4; mf++)                                                \
      a[mf] = *(const bf16x8*)&Ls[abase + 4096 + mf * 1024 + xo1];                \
    if ((T_) + 2 < NT) { stageA((T_) + 2, 0, S_); stageB((T_) + 2, 0, S_); }      \
    __builtin_amdgcn_s_setprio(1);                                                \
    MFMA16Q(4);                                                                   \
    __builtin_amdgcn_s_setprio(0);                                                \
    LGKM0();                                                                      \
    if ((T_) + 2 < NT) { VMCNT(4); } else { VMCNT(0); }                           \
    SBAR();                                                                       \
  }

template <int MODE>
__global__ __launch_bounds__(512, 2) void gemm256_kernel(
    const unsigned short* __restrict__ A,
    const unsigned short* __restrict__ Bt,
    int K, int N,
    const float* __restrict__ bias,
    void* __restrict__ out)
{
  __shared__ unsigned short lds[2][32768];

  const int t = threadIdx.x;
  const int w = t >> 6, lane = t & 63;
  const int wm = w >> 2, wn = w & 3;
  const int c = lane & 15, g = lane >> 4;

  const int gx = gridDim.x;
  const int nwg = gx * gridDim.y;
  const int bid = xcd_swz(blockIdx.y * gx + blockIdx.x, nwg);
  const long bm = (long)(bid % gx) * 256;
  const long bn = (long)(bid / gx) * 256;
  const int NT = K >> 6;
  const size_t ks = (size_t)K;

  const int tr  = t >> 3;
  const int tc8 = (t & 7) * 8;
  const int sch = ((t & 7) ^ (tr & 7)) * 8;

  auto stageA = [&](int T, int mh, int s) {
    const int r0 = mh * 64 + tr;
    gload16(A + (bm + r0) * ks + T * 64 + sch,       &lds[s][r0 * 64 + tc8]);
    gload16(A + (bm + r0 + 128) * ks + T * 64 + sch, &lds[s][(r0 + 128) * 64 + tc8]);
  };
  auto stageB = [&](int T, int nh, int s) {
    const int r0 = nh * 32 + (tr & 31) + (tr >> 5) * 64;
    gload16(Bt + (bn + r0) * ks + T * 64 + sch,       &lds[s][16384 + r0 * 64 + tc8]);
    gload16(Bt + (bn + r0 + 128) * ks + T * 64 + sch, &lds[s][16384 + (r0 + 128) * 64 + tc8]);
  };

  f32x4 acc[8][4];
  #pragma unroll
  for (int i = 0; i < 8; i++)
    #pragma unroll
    for (int j = 0; j < 4; j++) acc[i][j] = (f32x4){0.f, 0.f, 0.f, 0.f};

  const int xo0 = ((0 + g) ^ (c & 7)) * 8;
  const int xo1 = ((4 + g) ^ (c & 7)) * 8;
  const int abase = (wm * 128 + c) * 64;
  const int bbase = 16384 + (wn * 64 + c) * 64;

  // prologue: tile0 full (8 loads) + tile1 A-mh0,B0 (4 loads)
  stageA(0, 0, 0); stageB(0, 0, 0); stageA(0, 1, 0); stageB(0, 1, 0);
  stageA(1, 0, 1); stageB(1, 0, 1);
  VMCNT(4);
  SBAR();

  bf16x8 a[4], b[4];

  for (int T = 0; T < NT; T += 2) {
    G256_TILE(T, 0);
    G256_TILE(T + 1, 1);
  }

  // ---------------- epilogue ----------------
  #pragma unroll
  for (int mf = 0; mf < 8; mf++) {
    const long row0 = bm + wm * 128 + mf * 16 + g * 4;
    #pragma unroll
    for (int nf = 0; nf < 4; nf++) {
      const long col = bn + wn * 64 + nf * 16 + c;
      #pragma unroll
      for (int r = 0; r < 4; r++) {
        const long row = row0 + r;
        float v = acc[mf][nf][r];
        if constexpr (MODE == EPA_QK) {
          // col in [0,4096): slot 0 -> Q (scaled), slot 1 -> K; both [B,H,S,D]
          const int slot = (int)(col >> 11);
          const long cc = col & 2047;
          const long hh = cc >> 7, dd = cc & 127;
          const long bb = row >> 11, ss = row & 2047;
          unsigned short* o = (unsigned short*)out;
          if (slot == 0)
            o[((bb * NH + hh) * SEQ + ss) * HD + dd] = f2bf(v * 0.08838834764831845f);
          else
            o[8388608 + ((bb * NH + hh) * SEQ + ss) * HD + dd] = f2bf(v);
        } else { // EPA_FFN1: bias + tanh-GELU -> bf16
          float u = v + bias[col];
          float y = 0.7978845608028654f * (u + 0.044715f * u * u * u);
          float e = __expf(-2.0f * fabsf(y));
          float th = (1.0f - e) / (1.0f + e);
          th = (y < 0.0f) ? -th : th;
          ((unsigned short*)out)[row * (long)N + col] = f2bf(0.5f * u * (1.0f + th));
        }
      }
    }
  }
}

// ================= GEMM 128x256 (V / WO / FFN2) =================
// BK=64, 8 waves (2Mx4N), per-wave 64x64, LDS 96KB dbuf, 2 phases/K-tile,
// ONE barrier per phase (same discipline as gemm256). Counted vmcnt(4)/tile.
enum { EPB_V = 0, EPB_WO = 1, EPB_FFN2 = 2 };

#define MFMA16_128(NH_)                                                           \
    _Pragma("unroll")                                                             \
    for (int kk = 0; kk < 2; kk++)                                                \
      _Pragma("unroll")                                                           \
      for (int mh = 0; mh < 2; mh++)                                              \
        _Pragma("unroll")                                                         \
        for (int m = 0; m < 2; m++)                                               \
          _Pragma("unroll")                                                       \
          for (int n = 0; n < 2; n++)                                             \
            acc[mh][NH_][m][n] = __builtin_amdgcn_mfma_f32_16x16x32_bf16(         \
                a[mh][m][kk], b[n][kk], acc[mh][NH_][m][n], 0, 0, 0);

#define G128_TILE(T_, S_)                                                         \
  {                                                                               \
    const unsigned short* LA  = lds[S_][0];                                       \
    const unsigned short* LB0 = lds[S_][1];                                       \
    const unsigned short* LB1 = lds[S_][2];                                       \
    _Pragma("unroll")                                                             \
    for (int mh = 0; mh < 2; mh++)                                                \
      _Pragma("unroll")                                                           \
      for (int m = 0; m < 2; m++) {                                               \
        a[mh][m][0] = *(const bf16x8*)&LA[arow + mh * 2048 + m * 1024 + k0o];     \
        a[mh][m][1] = *(const bf16x8*)&LA[arow + mh * 2048 + m * 1024 + k1o];     \
      }                                                                           \
    _Pragma("unroll")                                                             \
    for (int n = 0; n < 2; n++) {                                                 \
      b[n][0] = *(const bf16x8*)&LB0[brow + n * 1024 + k0o];                      \
      b[n][1] = *(const bf16x8*)&LB0[brow + n * 1024 + k1o];                      \
    }                                                                             \
    if ((T_) + 1 < NT) stB((T_) + 1, 1, (S_) ^ 1);                                \
    __builtin_amdgcn_s_setprio(1);                                                \
    MFMA16_128(0);                                                                \
    __builtin_amdgcn_s_setprio(0);                                                \
    LGKM0();                                                                      \
    SBAR();                                                                       \
    _Pragma("unroll")                                                             \
    for (int n = 0; n < 2; n++) {                                                 \
      b[n][0] = *(const bf16x8*)&LB1[brow + n * 1024 + k0o];                      \
      b[n][1] = *(const bf16x8*)&LB1[brow + n * 1024 + k1o];                      \
    }                                                                             \
    if ((T_) + 2 < NT) { stA((T_) + 2, S_); stB((T_) + 2, 0, S_); }               \
    __builtin_amdgcn_s_setprio(1);                                                \
    MFMA16_128(1);                                                                \
    __builtin_amdgcn_s_setprio(0);                                                \
    LGKM0();                                                                      \
    if ((T_) + 2 < NT) { VMCNT(4); } else { VMCNT(0); }                           \
    SBAR();                                                                       \
  }

template <int MODE>
__global__ __launch_bounds__(512, 2) void gemm128_kernel(
    const unsigned short* __restrict__ A,
    const unsigned short* __restrict__ Bt,
    int K, int N,
    const float* __restrict__ res,
    const float* __restrict__ bias,
    void* __restrict__ out)
{
  __shared__ unsigned short lds[2][3][8192];   // [slot][A,B0,B1][128 x 64]

  const int t = threadIdx.x;
  const int w = t >> 6, lane = t & 63;
  const int wm = w >> 2, wn = w & 3;
  const int c = lane & 15, g = lane >> 4;
  const int l3 = lane >> 3, l7 = lane & 7;

  const int gx = gridDim.x;
  const int nwg = gx * gridDim.y;
  const int bid = xcd_swz(blockIdx.y * gx + blockIdx.x, nwg);
  const long bm = (long)(bid % gx) * 128;
  const long bn = (long)(bid / gx) * 256;
  const int NT = K >> 6;
  const size_t Ksz = (size_t)K;

  const int scol = (l7 ^ l3) * 8;
  const int r0a = w * 16;

  auto stA = [&](int T, int s) {
    unsigned short* d = &lds[s][0][r0a * 64];
    #pragma unroll
    for (int j = 0; j < 2; j++)
      gload16(A + (bm + r0a + j * 8 + l3) * Ksz + T * 64 + scol, d + j * 512);
  };
  auto stB = [&](int T, int nh, int s) {
    unsigned short* d = &lds[s][1 + nh][r0a * 64];
    #pragma unroll
    for (int j = 0; j < 2; j++)
      gload16(Bt + (bn + nh * 128 + r0a + j * 8 + l3) * Ksz + T * 64 + scol, d + j * 512);
  };

  f32x4 acc[2][2][2][2];
  #pragma unroll
  for (int i = 0; i < 2; i++)
    #pragma unroll
    for (int jq = 0; jq < 2; jq++)
      #pragma unroll
      for (int m = 0; m < 2; m++)
        #pragma unroll
        for (int n = 0; n < 2; n++) acc[i][jq][m][n] = (f32x4){0.f, 0.f, 0.f, 0.f};

  stA(0, 0); stB(0, 0, 0); stB(0, 1, 0);
  stA(1, 1); stB(1, 0, 1);
  VMCNT(4);
  SBAR();

  const int arow = (wm * 64 + c) * 64;
  const int brow = (wn * 32 + c) * 64;
  const int k0o = (g ^ (c & 7)) * 8;
  const int k1o = ((4 | g) ^ (c & 7)) * 8;

  bf16x8 a[2][2][2], b[2][2];

  for (int T = 0; T < NT; T += 2) {
    G128_TILE(T, 0);
    G128_TILE(T + 1, 1);
  }

  // ---------------- epilogue ----------------
  #pragma unroll
  for (int mh = 0; mh < 2; mh++)
    #pragma unroll
    for (int nh = 0; nh < 2; nh++)
      #pragma unroll
      for (int m = 0; m < 2; m++)
        #pragma unroll
        for (int n = 0; n < 2; n++) {
          const long row0 = bm + wm * 64 + mh * 32 + m * 16 + g * 4;
          const long col  = bn + nh * 128 + wn * 32 + n * 16 + c;
          #pragma unroll
          for (int r = 0; r < 4; r++) {
            const long row = row0 + r;
            float v = acc[mh][nh][m][n][r];
            if constexpr (MODE == EPB_V) {
              // V output scattered transposed to [B,H,D,S]
              const long hh = col >> 7, dd = col & 127;
              const long bb = row >> 11, ss = row & 2047;
              ((unsigned short*)out)[((bb * NH + hh) * HD + dd) * SEQ + ss] = f2bf(v);
            } else if constexpr (MODE == EPB_WO) {
              ((float*)out)[row * DM + col] = res[row * DM + col] + v;
            } else { // EPB_FFN2
              ((float*)out)[row * DM + col] = res[row * DM + col] + v + bias[col];
            }
          }
        }
}

// ---------------- Flash attention, causal + alibi, LDS-staged K/V ----------------
__global__ __launch_bounds__(256) void attn_kernel(
    const unsigned short* __restrict__ Q,
    const unsigned short* __restrict__ Kg,
    const unsigned short* __restrict__ Vt,
    const float* __restrict__ alibi,
    unsigned short* __restrict__ Out)
{
  __shared__ unsigned short lds[2][16384];   // 2 x (16KB K | 16KB V)

  const int bh = blockIdx.x;
  const int h = bh & (NH - 1);
  const int b = bh >> 4;
  const int j = blockIdx.y;
  const int t = threadIdx.x;
  const int w = t >> 6;
  const int lane = t & 63;
  const int c = lane & 15, g = lane >> 4;
  const int cx = (c & 7) << 4;

  const char* KpB = (const char*)(Kg + (size_t)bh * SEQ * HD);
  const char* VpB = (const char*)(Vt + (size_t)bh * SEQ * HD);
  const unsigned short* Qp = Q + (size_t)bh * SEQ * HD;
  const float* Ah = alibi + (size_t)h * SEQ * SEQ;

  #pragma unroll 1
  for (int half = 0; half < 2; half++) {
    const int cidx = half ? (31 - j) : j;
    const int nt = cidx + 1;
    const int qb = cidx * 64;
    const int q0 = qb + w * 16, qc = q0 + c;

    bf16x8 qf[4];
    #pragma unroll
    for (int dt = 0; dt < 4; dt++)
      qf[dt] = *(const bf16x8*)(Qp + (size_t)qc * HD + dt * 32 + g * 8);

    f32x4 oacc[8];
    #pragma unroll
    for (int d = 0; d < 8; d++) oacc[d] = (f32x4){0.f, 0.f, 0.f, 0.f};
    float m_run = -1e30f, s_run = 0.f;
    const float* Ap = Ah + (size_t)qc * SEQ;

    auto stage = [&](int tt, unsigned short* dst) {
      const size_t kvo = (size_t)tt * 64;
      #pragma unroll
      for (int k = 0; k < 8; k++) {
        const int o = w * 8192 + k * 1024 + lane * 16;
        if (w < 2) {
          const int so = o ^ (((o >> 8) & 7) << 4);
          gload16(KpB + kvo * 256 + so, dst + ((w * 8192 + k * 1024) >> 1));
        } else {
          const int o2 = o - 16384;
          const int d = o2 >> 7, win = o2 & 127;
          gload16(VpB + (size_t)d * 4096 + kvo * 2 + (win ^ ((d & 7) << 4)),
                  dst + ((w * 8192 + k * 1024) >> 1));
        }
      }
    };

    stage(0, lds[0]);
    __syncthreads();
    int buf = 0;

    for (int tt = 0; tt < nt; tt++) {
      if (tt + 1 < nt) stage(tt + 1, lds[buf ^ 1]);
      const unsigned short* LK = lds[buf];
      const unsigned short* LV = lds[buf] + 8192;
      const int kv0 = tt * 64;

      f32x4 sc[4];
      #pragma unroll
      for (int st = 0; st < 4; st++) sc[st] = (f32x4){0.f, 0.f, 0.f, 0.f};
      #pragma unroll
      for (int dt = 0; dt < 4; dt++)
        #pragma unroll
        for (int st = 0; st < 4; st++) {
          bf16x8 kf = *(const bf16x8*)&LK[(st * 4096 + c * 256 + ((dt * 64 + g * 16) ^ cx)) >> 1];
          sc[st] = __builtin_amdgcn_mfma_f32_16x16x32_bf16(kf, qf[dt], sc[st], 0, 0, 0);
        }

      float4 al[4];
      #pragma unroll
      for (int st = 0; st < 4; st++) al[st] = *(const float4*)(Ap + kv0 + st * 16 + g * 4);
      float scr[16];
      #pragma unroll
      for (int st = 0; st < 4; st++) {
        scr[st*4+0] = (kv0 + st*16 + g*4 + 0 > qc) ? -1e30f : sc[st][0] + al[st].x;
        scr[st*4+1] = (kv0 + st*16 + g*4 + 1 > qc) ? -1e30f : sc[st][1] + al[st].y;
        scr[st*4+2] = (kv0 + st*16 + g*4 + 2 > qc) ? -1e30f : sc[st][2] + al[st].z;
        scr[st*4+3] = (kv0 + st*16 + g*4 + 3 > qc) ? -1e30f : sc[st][3] + al[st].w;
      }

      float tm = scr[0];
      #pragma unroll
      for (int i = 1; i < 16; i++) tm = fmaxf(tm, scr[i]);
      tm = fmaxf(tm, __shfl_xor(tm, 16));
      tm = fmaxf(tm, __shfl_xor(tm, 32));
      const float m_new = fmaxf(m_run, tm);
      const float corr = __expf(m_run - m_new);
      float pv[16]; float ps = 0.f;
      #pragma unroll
      for (int i = 0; i < 16; i++) { pv[i] = __expf(scr[i] - m_new); ps += pv[i]; }
      ps += __shfl_xor(ps, 16);
      ps += __shfl_xor(ps, 32);
      s_run = s_run * corr + ps;
      m_run = m_new;

      short4_t pf[4];
      #pragma unroll
      for (int st = 0; st < 4; st++) {
        pf[st][0] = (short)f2bf(pv[st*4+0]); pf[st][1] = (short)f2bf(pv[st*4+1]);
        pf[st][2] = (short)f2bf(pv[st*4+2]); pf[st][3] = (short)f2bf(pv[st*4+3]);
      }

      float cf[4];
      #pragma unroll
      for (int r = 0; r < 4; r++) cf[r] = __shfl(corr, g * 4 + r);

      #pragma unroll
      for (int dt = 0; dt < 8; dt++) {
        f32x4 o = oacc[dt];
        o[0] *= cf[0]; o[1] *= cf[1]; o[2] *= cf[2]; o[3] *= cf[3];
        #pragma unroll
        for (int st = 0; st < 4; st++) {
          short4_t vf = *(const short4_t*)&LV[((dt * 16 + c) * 128 + ((st * 32 + g * 8) ^ cx)) >> 1];
          o = __builtin_amdgcn_mfma_f32_16x16x16bf16_1k(pf[st], vf, o, 0, 0, 0);
        }
        oacc[dt] = o;
      }

      __syncthreads();
      buf ^= 1;
    }

    float inv[4];
    #pragma unroll
    for (int r = 0; r < 4; r++) inv[r] = 1.0f / __shfl(s_run, g * 4 + r);
    #pragma unroll
    for (int dt = 0; dt < 8; dt++)
      #pragma unroll
      for (int r = 0; r < 4; r++)
        Out[(size_t)(b * SEQ + q0 + g * 4 + r) * DM + h * HD + dt * 16 + c] =
            f2bf(oacc[dt][r] * inv[r]);
  }
}

// ---------------- launch ----------------
extern "C" void kernel_launch(void* const* d_in, const int* in_sizes, int n_in,
                              void* d_out, int out_size, void* d_ws, size_t ws_size,
                              hipStream_t stream) {
  const float* x     = (const float*)d_in[0];
  const float* alibi = (const float*)d_in[1];
  const float* Wq    = (const float*)d_in[2];
  const float* Wk    = (const float*)d_in[3];
  const float* Wv    = (const float*)d_in[4];
  const float* Wo    = (const float*)d_in[5];
  const float* ln1g  = (const float*)d_in[6];
  const float* ln1b  = (const float*)d_in[7];
  const float* ln2g  = (const float*)d_in[8];
  const float* ln2b  = (const float*)d_in[9];
  const float* w1    = (const float*)d_in[10];
  const float* b1    = (const float*)d_in[11];
  const float* w2    = (const float*)d_in[12];
  const float* b2    = (const float*)d_in[13];

  char* ws = (char*)d_ws;
  float*          hbuf = (float*)(ws);                                // 32MB f32 h
  unsigned short* xn   = (unsigned short*)(ws + (32ull  << 20));      // 16MB bf16
  unsigned short* qb   = (unsigned short*)(ws + (48ull  << 20));      // Q|K 32MB
  unsigned short* kb   = (unsigned short*)(ws + (64ull  << 20));
  unsigned short* vt   = (unsigned short*)(ws + (80ull  << 20));      // V^T 16MB
  unsigned short* ao   = (unsigned short*)(ws + (96ull  << 20));      // 16MB attn out
  unsigned short* wt   = (unsigned short*)(ws + (112ull << 20));      // 34MB weights
  unsigned short* a1   = (unsigned short*)(ws + (48ull  << 20));      // 64MB FFN1 out

  dim3 blk256(256);
  dim3 blk512(512);
  dim3 tb(32, 8);

  ln_kernel<<<MROWS, blk256, 0, stream>>>(x, ln1g, ln1b, xn);
  transpose4_kernel<<<dim3(DM/32, DM/32, 4), tb, 0, stream>>>(Wq, Wk, Wv, Wo, wt);

  // QK fused: N=4096, 256 blocks (exact round)
  gemm256_kernel<EPA_QK><<<dim3(MROWS/256, (2*DM)/256), blk512, 0, stream>>>(
      xn, wt, DM, 2*DM, nullptr, qb);
  // V: N=2048, 256 blocks (exact round), transposed epilogue
  gemm128_kernel<EPB_V><<<dim3(MROWS/128, DM/256), blk512, 0, stream>>>(
      xn, wt + 2ull * DM * DM, DM, DM, nullptr, nullptr, vt);

  attn_kernel<<<dim3(NH * 2, 16), blk256, 0, stream>>>(qb, kb, vt, alibi, ao);

  // WO: hbuf = x + ao @ Wo^T   (256 blocks)
  gemm128_kernel<EPB_WO><<<dim3(MROWS/128, DM/256), blk512, 0, stream>>>(
      ao, wt + 3ull * DM * DM, DM, DM, x, nullptr, hbuf);

  ln_kernel<<<MROWS, blk256, 0, stream>>>(hbuf, ln2g, ln2b, xn);

  transpose_kernel<<<dim3(DFF/32, DM/32), tb, 0, stream>>>(w1, wt, DM, DFF);
  gemm256_kernel<EPA_FFN1><<<dim3(MROWS/256, DFF/256), blk512, 0, stream>>>(
      xn, wt, DM, DFF, b1, a1);

  transpose_kernel<<<dim3(DM/32, DFF/32), tb, 0, stream>>>(w2, wt, DFF, DM);
  // FFN2: d_out = hbuf + a1 @ w2^T + b2   (256 blocks)
  gemm128_kernel<EPB_FFN2><<<dim3(MROWS/128, DM/256), blk512, 0, stream>>>(
      a1, wt, DFF, DM, hbuf, b2, (float*)d_out);
}

// Round 13
// 612.122 us; speedup vs baseline: 1.2424x; 1.0420x over previous
//
#include <hip/hip_runtime.h>
#include <math.h>

#define DM   2048
#define DFF  8192
#define NH   16
#define HD   128
#define SEQ  2048
#define MROWS 4096   // BATCH * SEQ

typedef __attribute__((ext_vector_type(4))) float  f32x4;
typedef __attribute__((ext_vector_type(8))) __bf16 bf16x8;
typedef __attribute__((ext_vector_type(4))) short  short4_t;

#define VMCNT(n) asm volatile("s_waitcnt vmcnt(" #n ")" ::: "memory")
#define LGKM0()  asm volatile("s_waitcnt lgkmcnt(0)" ::: "memory")
#define SBAR()   asm volatile("s_barrier" ::: "memory")

__device__ inline unsigned short f2bf(float f) {
  union { float f; unsigned int u; } x; x.f = f;
  unsigned int r = x.u + 0x7FFFu + ((x.u >> 16) & 1u);
  return (unsigned short)(r >> 16);
}

__device__ inline unsigned int f2bf2(float lo, float hi) {
  return (unsigned int)f2bf(lo) | ((unsigned int)f2bf(hi) << 16);
}

__device__ inline void gload16(const void* g, void* l) {
  __builtin_amdgcn_global_load_lds(
      (const __attribute__((address_space(1))) unsigned int*)g,
      (__attribute__((address_space(3))) unsigned int*)l, 16, 0, 0);
}

// XCD-bijective block swizzle (valid because all our grids have nwg % 8 == 0)
__device__ inline int xcd_swz(int bid, int nwg) {
  return (bid & 7) * (nwg >> 3) + (bid >> 3);
}

// ---------------- LayerNorm (f32 in, bf16 out) ----------------
__global__ __launch_bounds__(256) void ln_kernel(
    const float* __restrict__ in, const float* __restrict__ gw,
    const float* __restrict__ bw, unsigned short* __restrict__ out)
{
  const int row = blockIdx.x;
  const float* xr = in + (size_t)row * DM;
  const int t = threadIdx.x, lane = t & 63, w = t >> 6;
  float4 v0 = ((const float4*)xr)[t];
  float4 v1 = ((const float4*)xr)[t + 256];
  float s = v0.x+v0.y+v0.z+v0.w + v1.x+v1.y+v1.z+v1.w;
  float s2 = v0.x*v0.x+v0.y*v0.y+v0.z*v0.z+v0.w*v0.w
           + v1.x*v1.x+v1.y*v1.y+v1.z*v1.z+v1.w*v1.w;
  #pragma unroll
  for (int off = 32; off; off >>= 1) { s += __shfl_xor(s, off); s2 += __shfl_xor(s2, off); }
  __shared__ float rs[4], rs2[4];
  if (lane == 0) { rs[w] = s; rs2[w] = s2; }
  __syncthreads();
  s = rs[0] + rs[1] + rs[2] + rs[3];
  s2 = rs2[0] + rs2[1] + rs2[2] + rs2[3];
  const float mu = s * (1.0f / DM);
  const float var = s2 * (1.0f / DM) - mu * mu;
  const float rstd = rsqrtf(var + 1e-5f);
  float4 g0 = ((const float4*)gw)[t],     b0 = ((const float4*)bw)[t];
  float4 g1 = ((const float4*)gw)[t+256], b1 = ((const float4*)bw)[t+256];
  unsigned short* o = out + (size_t)row * DM;
  int i0 = t * 4, i1 = (t + 256) * 4;
  o[i0+0] = f2bf((v0.x-mu)*rstd*g0.x + b0.x);
  o[i0+1] = f2bf((v0.y-mu)*rstd*g0.y + b0.y);
  o[i0+2] = f2bf((v0.z-mu)*rstd*g0.z + b0.z);
  o[i0+3] = f2bf((v0.w-mu)*rstd*g0.w + b0.w);
  o[i1+0] = f2bf((v1.x-mu)*rstd*g1.x + b1.x);
  o[i1+1] = f2bf((v1.y-mu)*rstd*g1.y + b1.y);
  o[i1+2] = f2bf((v1.z-mu)*rstd*g1.z + b1.z);
  o[i1+3] = f2bf((v1.w-mu)*rstd*g1.w + b1.w);
}

// ------- vectorized weight transpose + f32->bf16: in[nrows][ncols] -> out[ncols][nrows]
// 64x64 tile, 256 threads. float4 loads -> LDS [64][65] -> 16B packed-bf16 stores
// (8 orig-rows per store; 8 threads per col-group write 128B contiguous).
__global__ __launch_bounds__(256) void transpose_kernel(
    const float* __restrict__ in, unsigned short* __restrict__ out,
    int nrows, int ncols)
{
  __shared__ float tile[64][65];
  const int bx = blockIdx.x * 64;  // col base
  const int by = blockIdx.y * 64;  // row base
  const int t = threadIdx.x;
  const int lr = t >> 4;           // 0..15
  const int lc = (t & 15) * 4;     // 0..60
  #pragma unroll
  for (int i = 0; i < 4; i++) {
    const float4 v = *(const float4*)&in[(size_t)(by + i * 16 + lr) * ncols + bx + lc];
    tile[i * 16 + lr][lc + 0] = v.x;
    tile[i * 16 + lr][lc + 1] = v.y;
    tile[i * 16 + lr][lc + 2] = v.z;
    tile[i * 16 + lr][lc + 3] = v.w;
  }
  __syncthreads();
  const int oc0 = t >> 3;          // 0..31
  const int orr = (t & 7) * 8;     // 0..56
  #pragma unroll
  for (int i = 0; i < 2; i++) {
    const int col = oc0 + i * 32;
    uint4 v;
    v.x = f2bf2(tile[orr + 0][col], tile[orr + 1][col]);
    v.y = f2bf2(tile[orr + 2][col], tile[orr + 3][col]);
    v.z = f2bf2(tile[orr + 4][col], tile[orr + 5][col]);
    v.w = f2bf2(tile[orr + 6][col], tile[orr + 7][col]);
    *(uint4*)&out[(size_t)(bx + col) * nrows + by + orr] = v;
  }
}

// ------- batched vectorized transpose of the 4 DM x DM weights into wt -------
__global__ __launch_bounds__(256) void transpose4_kernel(
    const float* __restrict__ w0, const float* __restrict__ w1,
    const float* __restrict__ w2, const float* __restrict__ w3,
    unsigned short* __restrict__ out)
{
  __shared__ float tile[64][65];
  const float* srcs[4] = {w0, w1, w2, w3};
  const float* in = srcs[blockIdx.z];
  unsigned short* o = out + (size_t)blockIdx.z * DM * DM;
  const int bx = blockIdx.x * 64;
  const int by = blockIdx.y * 64;
  const int t = threadIdx.x;
  const int lr = t >> 4;
  const int lc = (t & 15) * 4;
  #pragma unroll
  for (int i = 0; i < 4; i++) {
    const float4 v = *(const float4*)&in[(size_t)(by + i * 16 + lr) * DM + bx + lc];
    tile[i * 16 + lr][lc + 0] = v.x;
    tile[i * 16 + lr][lc + 1] = v.y;
    tile[i * 16 + lr][lc + 2] = v.z;
    tile[i * 16 + lr][lc + 3] = v.w;
  }
  __syncthreads();
  const int oc0 = t >> 3;
  const int orr = (t & 7) * 8;
  #pragma unroll
  for (int i = 0; i < 2; i++) {
    const int col = oc0 + i * 32;
    uint4 v;
    v.x = f2bf2(tile[orr + 0][col], tile[orr + 1][col]);
    v.y = f2bf2(tile[orr + 2][col], tile[orr + 3][col]);
    v.z = f2bf2(tile[orr + 4][col], tile[orr + 5][col]);
    v.w = f2bf2(tile[orr + 6][col], tile[orr + 7][col]);
    *(uint4*)&o[(size_t)(bx + col) * DM + by + orr] = v;
  }
}

// ================= GEMM 256x256 (QK / FFN1) =================
// BK=64, 8 waves (2Mx4N), per-wave 128x64, LDS 128KB dbuf, chunk-swizzled.
// ONE barrier per phase: each wave's MFMA depends only on its OWN ds_reads
// (compiler-precise lgkmcnt); stage legality uses the phase-END LGKM0+SBAR
// seal. Waves desync within a phase -> LDS-read bursts overlap other waves'
// MFMA bursts; setprio(1) arbitrates toward MFMA. Counted vmcnt(4)/K-tile.
enum { EPA_QK = 0, EPA_FFN1 = 1 };

#define MFMA16Q(MB_)                                                              \
    _Pragma("unroll")                                                             \
    for (int mf = 0; mf < 4; mf++)                                                \
      _Pragma("unroll")                                                           \
      for (int nf = 0; nf < 4; nf++)                                              \
        acc[(MB_) + mf][nf] = __builtin_amdgcn_mfma_f32_16x16x32_bf16(            \
            a[mf], b[nf], acc[(MB_) + mf][nf], 0, 0, 0);

#define G256_TILE(T_, S_)                                                         \
  {                                                                               \
    const unsigned short* Ls = lds[S_];                                           \
    /* ---- ph0: kk0, mh0 ---- */                                                 \
    _Pragma("unroll")                                                             \
    for (int mf = 0; mf < 4; mf++)                                                \
      a[mf] = *(const bf16x8*)&Ls[abase + mf * 1024 + xo0];                       \
    _Pragma("unroll")                                                             \
    for (int nf = 0; nf < 4; nf++)                                                \
      b[nf] = *(const bf16x8*)&Ls[bbase + nf * 1024 + xo0];                       \
    if ((T_) + 1 < NT) stageA((T_) + 1, 1, (S_) ^ 1);                             \
    __builtin_amdgcn_s_setprio(1);                                                \
    MFMA16Q(0);                                                                   \
    __builtin_amdgcn_s_setprio(0);                                                \
    LGKM0();                                                                      \
    SBAR();                                                                       \
    /* ---- ph1: kk0, mh1 ---- */                                                 \
    _Pragma("unroll")                                                             \
    for (int mf = 0; mf < 4; mf++)                                                \
      a[mf] = *(const bf16x8*)&Ls[abase + 4096 + mf * 1024 + xo0];                \
    if ((T_) + 1 < NT) stageB((T_) + 1, 1, (S_) ^ 1);                             \
    __builtin_amdgcn_s_setprio(1);                                                \
    MFMA16Q(4);                                                                   \
    __builtin_amdgcn_s_setprio(0);                                                \
    LGKM0();                                                                      \
    SBAR();                                                                       \
    /* ---- ph2: kk1, mh0 ---- */                                                 \
    _Pragma("unroll")                                                             \
    for (int mf = 0; mf < 4; mf++)                                                \
      a[mf] = *(const bf16x8*)&Ls[abase + mf * 1024 + xo1];                       \
    _Pragma("unroll")                                                             \
    for (int nf = 0; nf < 4; nf++)                                                \
      b[nf] = *(const bf16x8*)&Ls[bbase + nf * 1024 + xo1];                       \
    __builtin_amdgcn_s_setprio(1);                                                \
    MFMA16Q(0);                                                                   \
    __builtin_amdgcn_s_setprio(0);                                                \
    LGKM0();                                                                      \
    SBAR();                                                                       \
    /* ---- ph3: kk1, mh1 ---- */                                                 \
    _Pragma("unroll")                                                             \
    for (int mf = 0; mf < 4; mf++)                                                \
      a[mf] = *(const bf16x8*)&Ls[abase + 4096 + mf * 1024 + xo1];                \
    if ((T_) + 2 < NT) { stageA((T_) + 2, 0, S_); stageB((T_) + 2, 0, S_); }      \
    __builtin_amdgcn_s_setprio(1);                                                \
    MFMA16Q(4);                                                                   \
    __builtin_amdgcn_s_setprio(0);                                                \
    LGKM0();                                                                      \
    if ((T_) + 2 < NT) { VMCNT(4); } else { VMCNT(0); }                           \
    SBAR();                                                                       \
  }

template <int MODE>
__global__ __launch_bounds__(512, 2) void gemm256_kernel(
    const unsigned short* __restrict__ A,
    const unsigned short* __restrict__ Bt,
    int K, int N,
    const float* __restrict__ bias,
    void* __restrict__ out)
{
  __shared__ unsigned short lds[2][32768];

  const int t = threadIdx.x;
  const int w = t >> 6, lane = t & 63;
  const int wm = w >> 2, wn = w & 3;
  const int c = lane & 15, g = lane >> 4;

  const int gx = gridDim.x;
  const int nwg = gx * gridDim.y;
  const int bid = xcd_swz(blockIdx.y * gx + blockIdx.x, nwg);
  const long bm = (long)(bid % gx) * 256;
  const long bn = (long)(bid / gx) * 256;
  const int NT = K >> 6;
  const size_t ks = (size_t)K;

  const int tr  = t >> 3;
  const int tc8 = (t & 7) * 8;
  const int sch = ((t & 7) ^ (tr & 7)) * 8;

  auto stageA = [&](int T, int mh, int s) {
    const int r0 = mh * 64 + tr;
    gload16(A + (bm + r0) * ks + T * 64 + sch,       &lds[s][r0 * 64 + tc8]);
    gload16(A + (bm + r0 + 128) * ks + T * 64 + sch, &lds[s][(r0 + 128) * 64 + tc8]);
  };
  auto stageB = [&](int T, int nh, int s) {
    const int r0 = nh * 32 + (tr & 31) + (tr >> 5) * 64;
    gload16(Bt + (bn + r0) * ks + T * 64 + sch,       &lds[s][16384 + r0 * 64 + tc8]);
    gload16(Bt + (bn + r0 + 128) * ks + T * 64 + sch, &lds[s][16384 + (r0 + 128) * 64 + tc8]);
  };

  f32x4 acc[8][4];
  #pragma unroll
  for (int i = 0; i < 8; i++)
    #pragma unroll
    for (int j = 0; j < 4; j++) acc[i][j] = (f32x4){0.f, 0.f, 0.f, 0.f};

  const int xo0 = ((0 + g) ^ (c & 7)) * 8;
  const int xo1 = ((4 + g) ^ (c & 7)) * 8;
  const int abase = (wm * 128 + c) * 64;
  const int bbase = 16384 + (wn * 64 + c) * 64;

  // prologue: tile0 full (8 loads) + tile1 A-mh0,B0 (4 loads)
  stageA(0, 0, 0); stageB(0, 0, 0); stageA(0, 1, 0); stageB(0, 1, 0);
  stageA(1, 0, 1); stageB(1, 0, 1);
  VMCNT(4);
  SBAR();

  bf16x8 a[4], b[4];

  for (int T = 0; T < NT; T += 2) {
    G256_TILE(T, 0);
    G256_TILE(T + 1, 1);
  }

  // ---------------- epilogue ----------------
  #pragma unroll
  for (int mf = 0; mf < 8; mf++) {
    const long row0 = bm + wm * 128 + mf * 16 + g * 4;
    #pragma unroll
    for (int nf = 0; nf < 4; nf++) {
      const long col = bn + wn * 64 + nf * 16 + c;
      #pragma unroll
      for (int r = 0; r < 4; r++) {
        const long row = row0 + r;
        float v = acc[mf][nf][r];
        if constexpr (MODE == EPA_QK) {
          // col in [0,4096): slot 0 -> Q (scaled), slot 1 -> K; both [B,H,S,D]
          const int slot = (int)(col >> 11);
          const long cc = col & 2047;
          const long hh = cc >> 7, dd = cc & 127;
          const long bb = row >> 11, ss = row & 2047;
          unsigned short* o = (unsigned short*)out;
          if (slot == 0)
            o[((bb * NH + hh) * SEQ + ss) * HD + dd] = f2bf(v * 0.08838834764831845f);
          else
            o[8388608 + ((bb * NH + hh) * SEQ + ss) * HD + dd] = f2bf(v);
        } else { // EPA_FFN1: bias + tanh-GELU -> bf16
          float u = v + bias[col];
          float y = 0.7978845608028654f * (u + 0.044715f * u * u * u);
          float e = __expf(-2.0f * fabsf(y));
          float th = (1.0f - e) / (1.0f + e);
          th = (y < 0.0f) ? -th : th;
          ((unsigned short*)out)[row * (long)N + col] = f2bf(0.5f * u * (1.0f + th));
        }
      }
    }
  }
}

// ================= GEMM 128x256 (V / WO / FFN2) =================
// BK=64, 8 waves (2Mx4N), per-wave 64x64, LDS 96KB dbuf, 2 phases/K-tile,
// ONE barrier per phase (same discipline as gemm256). Counted vmcnt(4)/tile.
enum { EPB_V = 0, EPB_WO = 1, EPB_FFN2 = 2 };

#define MFMA16_128(NH_)                                                           \
    _Pragma("unroll")                                                             \
    for (int kk = 0; kk < 2; kk++)                                                \
      _Pragma("unroll")                                                           \
      for (int mh = 0; mh < 2; mh++)                                              \
        _Pragma("unroll")                                                         \
        for (int m = 0; m < 2; m++)                                               \
          _Pragma("unroll")                                                       \
          for (int n = 0; n < 2; n++)                                             \
            acc[mh][NH_][m][n] = __builtin_amdgcn_mfma_f32_16x16x32_bf16(         \
                a[mh][m][kk], b[n][kk], acc[mh][NH_][m][n], 0, 0, 0);

#define G128_TILE(T_, S_)                                                         \
  {                                                                               \
    const unsigned short* LA  = lds[S_][0];                                       \
    const unsigned short* LB0 = lds[S_][1];                                       \
    const unsigned short* LB1 = lds[S_][2];                                       \
    _Pragma("unroll")                                                             \
    for (int mh = 0; mh < 2; mh++)                                                \
      _Pragma("unroll")                                                           \
      for (int m = 0; m < 2; m++) {                                               \
        a[mh][m][0] = *(const bf16x8*)&LA[arow + mh * 2048 + m * 1024 + k0o];     \
        a[mh][m][1] = *(const bf16x8*)&LA[arow + mh * 2048 + m * 1024 + k1o];     \
      }                                                                           \
    _Pragma("unroll")                                                             \
    for (int n = 0; n < 2; n++) {                                                 \
      b[n][0] = *(const bf16x8*)&LB0[brow + n * 1024 + k0o];                      \
      b[n][1] = *(const bf16x8*)&LB0[brow + n * 1024 + k1o];                      \
    }                                                                             \
    if ((T_) + 1 < NT) stB((T_) + 1, 1, (S_) ^ 1);                                \
    __builtin_amdgcn_s_setprio(1);                                                \
    MFMA16_128(0);                                                                \
    __builtin_amdgcn_s_setprio(0);                                                \
    LGKM0();                                                                      \
    SBAR();                                                                       \
    _Pragma("unroll")                                                             \
    for (int n = 0; n < 2; n++) {                                                 \
      b[n][0] = *(const bf16x8*)&LB1[brow + n * 1024 + k0o];                      \
      b[n][1] = *(const bf16x8*)&LB1[brow + n * 1024 + k1o];                      \
    }                                                                             \
    if ((T_) + 2 < NT) { stA((T_) + 2, S_); stB((T_) + 2, 0, S_); }               \
    __builtin_amdgcn_s_setprio(1);                                                \
    MFMA16_128(1);                                                                \
    __builtin_amdgcn_s_setprio(0);                                                \
    LGKM0();                                                                      \
    if ((T_) + 2 < NT) { VMCNT(4); } else { VMCNT(0); }                           \
    SBAR();                                                                       \
  }

template <int MODE>
__global__ __launch_bounds__(512, 2) void gemm128_kernel(
    const unsigned short* __restrict__ A,
    const unsigned short* __restrict__ Bt,
    int K, int N,
    const float* __restrict__ res,
    const float* __restrict__ bias,
    void* __restrict__ out)
{
  __shared__ unsigned short lds[2][3][8192];   // [slot][A,B0,B1][128 x 64]

  const int t = threadIdx.x;
  const int w = t >> 6, lane = t & 63;
  const int wm = w >> 2, wn = w & 3;
  const int c = lane & 15, g = lane >> 4;
  const int l3 = lane >> 3, l7 = lane & 7;

  const int gx = gridDim.x;
  const int nwg = gx * gridDim.y;
  const int bid = xcd_swz(blockIdx.y * gx + blockIdx.x, nwg);
  const long bm = (long)(bid % gx) * 128;
  const long bn = (long)(bid / gx) * 256;
  const int NT = K >> 6;
  const size_t Ksz = (size_t)K;

  const int scol = (l7 ^ l3) * 8;
  const int r0a = w * 16;

  auto stA = [&](int T, int s) {
    unsigned short* d = &lds[s][0][r0a * 64];
    #pragma unroll
    for (int j = 0; j < 2; j++)
      gload16(A + (bm + r0a + j * 8 + l3) * Ksz + T * 64 + scol, d + j * 512);
  };
  auto stB = [&](int T, int nh, int s) {
    unsigned short* d = &lds[s][1 + nh][r0a * 64];
    #pragma unroll
    for (int j = 0; j < 2; j++)
      gload16(Bt + (bn + nh * 128 + r0a + j * 8 + l3) * Ksz + T * 64 + scol, d + j * 512);
  };

  f32x4 acc[2][2][2][2];
  #pragma unroll
  for (int i = 0; i < 2; i++)
    #pragma unroll
    for (int jq = 0; jq < 2; jq++)
      #pragma unroll
      for (int m = 0; m < 2; m++)
        #pragma unroll
        for (int n = 0; n < 2; n++) acc[i][jq][m][n] = (f32x4){0.f, 0.f, 0.f, 0.f};

  stA(0, 0); stB(0, 0, 0); stB(0, 1, 0);
  stA(1, 1); stB(1, 0, 1);
  VMCNT(4);
  SBAR();

  const int arow = (wm * 64 + c) * 64;
  const int brow = (wn * 32 + c) * 64;
  const int k0o = (g ^ (c & 7)) * 8;
  const int k1o = ((4 | g) ^ (c & 7)) * 8;

  bf16x8 a[2][2][2], b[2][2];

  for (int T = 0; T < NT; T += 2) {
    G128_TILE(T, 0);
    G128_TILE(T + 1, 1);
  }

  // ---------------- epilogue ----------------
  #pragma unroll
  for (int mh = 0; mh < 2; mh++)
    #pragma unroll
    for (int nh = 0; nh < 2; nh++)
      #pragma unroll
      for (int m = 0; m < 2; m++)
        #pragma unroll
        for (int n = 0; n < 2; n++) {
          const long row0 = bm + wm * 64 + mh * 32 + m * 16 + g * 4;
          const long col  = bn + nh * 128 + wn * 32 + n * 16 + c;
          #pragma unroll
          for (int r = 0; r < 4; r++) {
            const long row = row0 + r;
            float v = acc[mh][nh][m][n][r];
            if constexpr (MODE == EPB_V) {
              // V output scattered transposed to [B,H,D,S]
              const long hh = col >> 7, dd = col & 127;
              const long bb = row >> 11, ss = row & 2047;
              ((unsigned short*)out)[((bb * NH + hh) * HD + dd) * SEQ + ss] = f2bf(v);
            } else if constexpr (MODE == EPB_WO) {
              ((float*)out)[row * DM + col] = res[row * DM + col] + v;
            } else { // EPB_FFN2
              ((float*)out)[row * DM + col] = res[row * DM + col] + v + bias[col];
            }
          }
        }
}

// ---------------- Flash attention, causal + alibi, LDS-staged K/V ----------------
__global__ __launch_bounds__(256) void attn_kernel(
    const unsigned short* __restrict__ Q,
    const unsigned short* __restrict__ Kg,
    const unsigned short* __restrict__ Vt,
    const float* __restrict__ alibi,
    unsigned short* __restrict__ Out)
{
  __shared__ unsigned short lds[2][16384];   // 2 x (16KB K | 16KB V)

  const int bh = blockIdx.x;
  const int h = bh & (NH - 1);
  const int b = bh >> 4;
  const int j = blockIdx.y;
  const int t = threadIdx.x;
  const int w = t >> 6;
  const int lane = t & 63;
  const int c = lane & 15, g = lane >> 4;
  const int cx = (c & 7) << 4;

  const char* KpB = (const char*)(Kg + (size_t)bh * SEQ * HD);
  const char* VpB = (const char*)(Vt + (size_t)bh * SEQ * HD);
  const unsigned short* Qp = Q + (size_t)bh * SEQ * HD;
  const float* Ah = alibi + (size_t)h * SEQ * SEQ;

  #pragma unroll 1
  for (int half = 0; half < 2; half++) {
    const int cidx = half ? (31 - j) : j;
    const int nt = cidx + 1;
    const int qb = cidx * 64;
    const int q0 = qb + w * 16, qc = q0 + c;

    bf16x8 qf[4];
    #pragma unroll
    for (int dt = 0; dt < 4; dt++)
      qf[dt] = *(const bf16x8*)(Qp + (size_t)qc * HD + dt * 32 + g * 8);

    f32x4 oacc[8];
    #pragma unroll
    for (int d = 0; d < 8; d++) oacc[d] = (f32x4){0.f, 0.f, 0.f, 0.f};
    float m_run = -1e30f, s_run = 0.f;
    const float* Ap = Ah + (size_t)qc * SEQ;

    auto stage = [&](int tt, unsigned short* dst) {
      const size_t kvo = (size_t)tt * 64;
      #pragma unroll
      for (int k = 0; k < 8; k++) {
        const int o = w * 8192 + k * 1024 + lane * 16;
        if (w < 2) {
          const int so = o ^ (((o >> 8) & 7) << 4);
          gload16(KpB + kvo * 256 + so, dst + ((w * 8192 + k * 1024) >> 1));
        } else {
          const int o2 = o - 16384;
          const int d = o2 >> 7, win = o2 & 127;
          gload16(VpB + (size_t)d * 4096 + kvo * 2 + (win ^ ((d & 7) << 4)),
                  dst + ((w * 8192 + k * 1024) >> 1));
        }
      }
    };

    stage(0, lds[0]);
    __syncthreads();
    int buf = 0;

    for (int tt = 0; tt < nt; tt++) {
      if (tt + 1 < nt) stage(tt + 1, lds[buf ^ 1]);
      const unsigned short* LK = lds[buf];
      const unsigned short* LV = lds[buf] + 8192;
      const int kv0 = tt * 64;

      f32x4 sc[4];
      #pragma unroll
      for (int st = 0; st < 4; st++) sc[st] = (f32x4){0.f, 0.f, 0.f, 0.f};
      #pragma unroll
      for (int dt = 0; dt < 4; dt++)
        #pragma unroll
        for (int st = 0; st < 4; st++) {
          bf16x8 kf = *(const bf16x8*)&LK[(st * 4096 + c * 256 + ((dt * 64 + g * 16) ^ cx)) >> 1];
          sc[st] = __builtin_amdgcn_mfma_f32_16x16x32_bf16(kf, qf[dt], sc[st], 0, 0, 0);
        }

      float4 al[4];
      #pragma unroll
      for (int st = 0; st < 4; st++) al[st] = *(const float4*)(Ap + kv0 + st * 16 + g * 4);
      float scr[16];
      #pragma unroll
      for (int st = 0; st < 4; st++) {
        scr[st*4+0] = (kv0 + st*16 + g*4 + 0 > qc) ? -1e30f : sc[st][0] + al[st].x;
        scr[st*4+1] = (kv0 + st*16 + g*4 + 1 > qc) ? -1e30f : sc[st][1] + al[st].y;
        scr[st*4+2] = (kv0 + st*16 + g*4 + 2 > qc) ? -1e30f : sc[st][2] + al[st].z;
        scr[st*4+3] = (kv0 + st*16 + g*4 + 3 > qc) ? -1e30f : sc[st][3] + al[st].w;
      }

      float tm = scr[0];
      #pragma unroll
      for (int i = 1; i < 16; i++) tm = fmaxf(tm, scr[i]);
      tm = fmaxf(tm, __shfl_xor(tm, 16));
      tm = fmaxf(tm, __shfl_xor(tm, 32));
      const float m_new = fmaxf(m_run, tm);
      const float corr = __expf(m_run - m_new);
      float pv[16]; float ps = 0.f;
      #pragma unroll
      for (int i = 0; i < 16; i++) { pv[i] = __expf(scr[i] - m_new); ps += pv[i]; }
      ps += __shfl_xor(ps, 16);
      ps += __shfl_xor(ps, 32);
      s_run = s_run * corr + ps;
      m_run = m_new;

      short4_t pf[4];
      #pragma unroll
      for (int st = 0; st < 4; st++) {
        pf[st][0] = (short)f2bf(pv[st*4+0]); pf[st][1] = (short)f2bf(pv[st*4+1]);
        pf[st][2] = (short)f2bf(pv[st*4+2]); pf[st][3] = (short)f2bf(pv[st*4+3]);
      }

      float cf[4];
      #pragma unroll
      for (int r = 0; r < 4; r++) cf[r] = __shfl(corr, g * 4 + r);

      #pragma unroll
      for (int dt = 0; dt < 8; dt++) {
        f32x4 o = oacc[dt];
        o[0] *= cf[0]; o[1] *= cf[1]; o[2] *= cf[2]; o[3] *= cf[3];
        #pragma unroll
        for (int st = 0; st < 4; st++) {
          short4_t vf = *(const short4_t*)&LV[((dt * 16 + c) * 128 + ((st * 32 + g * 8) ^ cx)) >> 1];
          o = __builtin_amdgcn_mfma_f32_16x16x16bf16_1k(pf[st], vf, o, 0, 0, 0);
        }
        oacc[dt] = o;
      }

      __syncthreads();
      buf ^= 1;
    }

    float inv[4];
    #pragma unroll
    for (int r = 0; r < 4; r++) inv[r] = 1.0f / __shfl(s_run, g * 4 + r);
    #pragma unroll
    for (int dt = 0; dt < 8; dt++)
      #pragma unroll
      for (int r = 0; r < 4; r++)
        Out[(size_t)(b * SEQ + q0 + g * 4 + r) * DM + h * HD + dt * 16 + c] =
            f2bf(oacc[dt][r] * inv[r]);
  }
}

// ---------------- launch ----------------
extern "C" void kernel_launch(void* const* d_in, const int* in_sizes, int n_in,
                              void* d_out, int out_size, void* d_ws, size_t ws_size,
                              hipStream_t stream) {
  const float* x     = (const float*)d_in[0];
  const float* alibi = (const float*)d_in[1];
  const float* Wq    = (const float*)d_in[2];
  const float* Wk    = (const float*)d_in[3];
  const float* Wv    = (const float*)d_in[4];
  const float* Wo    = (const float*)d_in[5];
  const float* ln1g  = (const float*)d_in[6];
  const float* ln1b  = (const float*)d_in[7];
  const float* ln2g  = (const float*)d_in[8];
  const float* ln2b  = (const float*)d_in[9];
  const float* w1    = (const float*)d_in[10];
  const float* b1    = (const float*)d_in[11];
  const float* w2    = (const float*)d_in[12];
  const float* b2    = (const float*)d_in[13];

  char* ws = (char*)d_ws;
  float*          hbuf = (float*)(ws);                                // 32MB f32 h
  unsigned short* xn   = (unsigned short*)(ws + (32ull  << 20));      // 16MB bf16
  unsigned short* qb   = (unsigned short*)(ws + (48ull  << 20));      // Q|K 32MB
  unsigned short* kb   = (unsigned short*)(ws + (64ull  << 20));
  unsigned short* vt   = (unsigned short*)(ws + (80ull  << 20));      // V^T 16MB
  unsigned short* ao   = (unsigned short*)(ws + (96ull  << 20));      // 16MB attn out
  unsigned short* wt   = (unsigned short*)(ws + (112ull << 20));      // 34MB weights
  unsigned short* a1   = (unsigned short*)(ws + (48ull  << 20));      // 64MB FFN1 out

  dim3 blk256(256);
  dim3 blk512(512);

  ln_kernel<<<MROWS, blk256, 0, stream>>>(x, ln1g, ln1b, xn);
  transpose4_kernel<<<dim3(DM/64, DM/64, 4), blk256, 0, stream>>>(Wq, Wk, Wv, Wo, wt);

  // QK fused: N=4096, 256 blocks (exact round)
  gemm256_kernel<EPA_QK><<<dim3(MROWS/256, (2*DM)/256), blk512, 0, stream>>>(
      xn, wt, DM, 2*DM, nullptr, qb);
  // V: N=2048, 256 blocks (exact round), transposed epilogue
  gemm128_kernel<EPB_V><<<dim3(MROWS/128, DM/256), blk512, 0, stream>>>(
      xn, wt + 2ull * DM * DM, DM, DM, nullptr, nullptr, vt);

  attn_kernel<<<dim3(NH * 2, 16), blk256, 0, stream>>>(qb, kb, vt, alibi, ao);

  // WO: hbuf = x + ao @ Wo^T   (256 blocks)
  gemm128_kernel<EPB_WO><<<dim3(MROWS/128, DM/256), blk512, 0, stream>>>(
      ao, wt + 3ull * DM * DM, DM, DM, x, nullptr, hbuf);

  ln_kernel<<<MROWS, blk256, 0, stream>>>(hbuf, ln2g, ln2b, xn);

  transpose_kernel<<<dim3(DFF/64, DM/64), blk256, 0, stream>>>(w1, wt, DM, DFF);
  gemm256_kernel<EPA_FFN1><<<dim3(MROWS/256, DFF/256), blk512, 0, stream>>>(
      xn, wt, DM, DFF, b1, a1);

  transpose_kernel<<<dim3(DM/64, DFF/64), blk256, 0, stream>>>(w2, wt, DFF, DM);
  // FFN2: d_out = hbuf + a1 @ w2^T + b2   (256 blocks)
  gemm128_kernel<EPB_FFN2><<<dim3(MROWS/128, DM/256), blk512, 0, stream>>>(
      a1, wt, DFF, DM, hbuf, b2, (float*)d_out);
}